// Round 3
// baseline (931.369 us; speedup 1.0000x reference)
//
#include <hip/hip_runtime.h>
#include <hip/hip_bf16.h>

#define D_MODEL 768
#define D_INNER 1536
#define D_STATE 16
#define DT_RANK 48
#define SEQ 2048

typedef float f32x4 __attribute__((ext_vector_type(4)));
typedef short bf16x8 __attribute__((ext_vector_type(8)));

// round-to-nearest-even fp32 -> bf16 bits
__device__ __forceinline__ ushort f2bf_bits(float f) {
  uint u = __float_as_uint(f);
  u += 0x7FFFu + ((u >> 16) & 1u);
  return (ushort)(u >> 16);
}
__device__ __forceinline__ float bf_bits2f(ushort b) {
  return __uint_as_float(((uint)b) << 16);
}

// ---------------------------------------------------------------------------
// MFMA GEMM with on-the-fly 3-term bf16 split (C = Ahi·Bhi + Ahi·Blo + Alo·Bhi).
// A (M,K) fp32 row-major, B (N,K) fp32 row-major (i.e. computes A @ B^T).
// Tile BM x BN (multiples of 32), 256 threads = 4 waves in 2x2 grid.
// BK = 64. Requires M % BM == 0, N % BN == 0, K % 64 == 0.
// LDS rows padded to 72 ushorts (144B): frag ds_read_b128 at the 8-access floor.
// ---------------------------------------------------------------------------
template <int BM, int BN>
__global__ __launch_bounds__(256) void gemm_mfma_split(
    const float* __restrict__ A, int lda,
    const float* __restrict__ B, int ldb,
    float* __restrict__ C, int ldc, int K) {
  __shared__ __align__(16) ushort As_hi[BM][72];
  __shared__ __align__(16) ushort As_lo[BM][72];
  __shared__ __align__(16) ushort Bs_hi[BN][72];
  __shared__ __align__(16) ushort Bs_lo[BN][72];

  const int tid = threadIdx.x;
  const int lane = tid & 63;
  const int wave = tid >> 6;
  const int m0 = blockIdx.y * BM;
  const int n0 = blockIdx.x * BN;

  constexpr int FM = BM / 32;  // 16x16 frags per wave (m)
  constexpr int FN = BN / 32;
  const int wm0 = (wave >> 1) * (BM / 2);
  const int wn0 = (wave & 1) * (BN / 2);
  const int fr = lane & 15;   // row (A) / col (B) within fragment
  const int kg = lane >> 4;   // k-group: 8 contiguous k per lane

  f32x4 acc[FM][FN] = {};

  for (int k0 = 0; k0 < K; k0 += 64) {
    // ---- stage A: BM x 64 fp32 -> hi/lo bf16 in LDS ----
#pragma unroll
    for (int i = 0; i < BM / 16; ++i) {
      const int s = i * 256 + tid;          // vec4 slot
      const int row = s >> 4;               // 16 vec4 per 64-elem row
      const int c4 = (s & 15) << 2;
      const float4 v = *(const float4*)&A[(m0 + row) * lda + k0 + c4];
      const float f[4] = {v.x, v.y, v.z, v.w};
      ushort4 h, l;
      ushort* hp = (ushort*)&h;
      ushort* lp = (ushort*)&l;
#pragma unroll
      for (int j = 0; j < 4; ++j) {
        const ushort hb = f2bf_bits(f[j]);
        hp[j] = hb;
        lp[j] = f2bf_bits(f[j] - bf_bits2f(hb));
      }
      *(ushort4*)&As_hi[row][c4] = h;
      *(ushort4*)&As_lo[row][c4] = l;
    }
    // ---- stage B: BN x 64 ----
#pragma unroll
    for (int i = 0; i < BN / 16; ++i) {
      const int s = i * 256 + tid;
      const int row = s >> 4;
      const int c4 = (s & 15) << 2;
      const float4 v = *(const float4*)&B[(n0 + row) * ldb + k0 + c4];
      const float f[4] = {v.x, v.y, v.z, v.w};
      ushort4 h, l;
      ushort* hp = (ushort*)&h;
      ushort* lp = (ushort*)&l;
#pragma unroll
      for (int j = 0; j < 4; ++j) {
        const ushort hb = f2bf_bits(f[j]);
        hp[j] = hb;
        lp[j] = f2bf_bits(f[j] - bf_bits2f(hb));
      }
      *(ushort4*)&Bs_hi[row][c4] = h;
      *(ushort4*)&Bs_lo[row][c4] = l;
    }
    __syncthreads();

    // ---- MFMA: 2 k-steps of 32 ----
#pragma unroll
    for (int k2 = 0; k2 < 64; k2 += 32) {
      bf16x8 ah[FM], al[FM];
#pragma unroll
      for (int m = 0; m < FM; ++m) {
        ah[m] = *(const bf16x8*)&As_hi[wm0 + m * 16 + fr][k2 + kg * 8];
        al[m] = *(const bf16x8*)&As_lo[wm0 + m * 16 + fr][k2 + kg * 8];
      }
#pragma unroll
      for (int n = 0; n < FN; ++n) {
        const bf16x8 bh = *(const bf16x8*)&Bs_hi[wn0 + n * 16 + fr][k2 + kg * 8];
        const bf16x8 bl = *(const bf16x8*)&Bs_lo[wn0 + n * 16 + fr][k2 + kg * 8];
#pragma unroll
        for (int m = 0; m < FM; ++m) {
          acc[m][n] = __builtin_amdgcn_mfma_f32_16x16x32_bf16(ah[m], bh, acc[m][n], 0, 0, 0);
          acc[m][n] = __builtin_amdgcn_mfma_f32_16x16x32_bf16(ah[m], bl, acc[m][n], 0, 0, 0);
          acc[m][n] = __builtin_amdgcn_mfma_f32_16x16x32_bf16(al[m], bh, acc[m][n], 0, 0, 0);
        }
      }
    }
    __syncthreads();
  }

  // ---- epilogue: C/D layout col=lane&15, row=(lane>>4)*4+reg ----
#pragma unroll
  for (int m = 0; m < FM; ++m) {
#pragma unroll
    for (int n = 0; n < FN; ++n) {
      const int row = m0 + wm0 + m * 16 + (lane >> 4) * 4;
      const int col = n0 + wn0 + n * 16 + (lane & 15);
#pragma unroll
      for (int r = 0; r < 4; ++r) C[(row + r) * ldc + col] = acc[m][n][r];
    }
  }
}

// ---------------------------------------------------------------------------
// fp32 fallback GEMM (used for the small GEMMs): C = f(A @ B^T [+ bias])
// MODE 0: plain. MODE 1: softplus(acc + bias[n]). 64x64 tile, BK=16.
// ---------------------------------------------------------------------------
template <int MODE>
__global__ __launch_bounds__(256) void gemm_kernel(
    const float* __restrict__ A, int lda,
    const float* __restrict__ B, int ldb,
    const float* __restrict__ bias,
    float* __restrict__ C, int ldc,
    int M, int N, int K) {
  __shared__ __align__(16) float As[16][68];
  __shared__ __align__(16) float Bs[16][68];

  const int tid = threadIdx.x;
  const int tx = tid & 15;
  const int ty = tid >> 4;
  const int m0 = blockIdx.y * 64;
  const int n0 = blockIdx.x * 64;

  const int am = tid >> 2;
  const int ak = (tid & 3) << 2;

  float acc[4][4] = {};

  for (int k0 = 0; k0 < K; k0 += 16) {
    {
      const float4 av = *(const float4*)&A[(m0 + am) * lda + k0 + ak];
      As[ak + 0][am] = av.x;
      As[ak + 1][am] = av.y;
      As[ak + 2][am] = av.z;
      As[ak + 3][am] = av.w;
    }
    {
      const int bn = n0 + am;
      float4 bv = make_float4(0.f, 0.f, 0.f, 0.f);
      if (bn < N) bv = *(const float4*)&B[bn * ldb + k0 + ak];
      Bs[ak + 0][am] = bv.x;
      Bs[ak + 1][am] = bv.y;
      Bs[ak + 2][am] = bv.z;
      Bs[ak + 3][am] = bv.w;
    }
    __syncthreads();

#pragma unroll
    for (int k = 0; k < 16; ++k) {
      const float4 a = *(const float4*)&As[k][ty * 4];
      const float4 b = *(const float4*)&Bs[k][tx * 4];
      const float ar[4] = {a.x, a.y, a.z, a.w};
      const float br[4] = {b.x, b.y, b.z, b.w};
#pragma unroll
      for (int i = 0; i < 4; ++i)
#pragma unroll
        for (int j = 0; j < 4; ++j) acc[i][j] = fmaf(ar[i], br[j], acc[i][j]);
    }
    __syncthreads();
  }

#pragma unroll
  for (int i = 0; i < 4; ++i) {
    const int m = m0 + ty * 4 + i;
#pragma unroll
    for (int j = 0; j < 4; ++j) {
      const int n = n0 + tx * 4 + j;
      if (n < N) {
        float v = acc[i][j];
        if (MODE == 1) {
          v += bias[n];
          v = (v > 20.f) ? v : log1pf(__expf(v));  // softplus
        }
        C[m * ldc + n] = v;
      }
    }
  }
}

// ---------------------------------------------------------------------------
// Depthwise causal conv (width 4) + bias + SiLU.
// ---------------------------------------------------------------------------
__global__ __launch_bounds__(256) void conv_silu_kernel(
    const float* __restrict__ xz, const float* __restrict__ cw,
    const float* __restrict__ cb, float* __restrict__ xbc) {
  const int idx = blockIdx.x * 256 + threadIdx.x;
  const int t = idx / D_INNER;
  const int d = idx - t * D_INNER;
  float acc = cb[d];
#pragma unroll
  for (int j = 0; j < 4; ++j) {
    const int tt = t + j - 3;
    if (tt >= 0) acc = fmaf(xz[tt * (2 * D_INNER) + d], cw[d * 4 + j], acc);
  }
  xbc[idx] = acc / (1.f + __expf(-acc));  // silu
}

// ---------------------------------------------------------------------------
// Selective scan, fused epilogue (+xbc*D, *silu(z)).
// ---------------------------------------------------------------------------
__global__ __launch_bounds__(256) void scan_kernel(
    const float* __restrict__ dt, const float* __restrict__ xdbl,
    const float* __restrict__ xbc, const float* __restrict__ xz,
    const float* __restrict__ A_log, const float* __restrict__ Dp,
    float* __restrict__ ym) {
  __shared__ float dt_s[64][16];
  __shared__ float xb_s[64][16];
  __shared__ float z_s[64][16];
  __shared__ float B_s[64][16];
  __shared__ float C_s[64][16];
  __shared__ float y_s[64][16];

  const int tid = threadIdx.x;
  const int ch = tid >> 4;
  const int n = tid & 15;
  const int d0 = blockIdx.x * 16;
  const int d = d0 + ch;

  const float Aval = -__expf(A_log[d * D_STATE + n]);
  const float Dval = Dp[d];
  float h = 0.f;

  for (int t0 = 0; t0 < SEQ; t0 += 64) {
    for (int f = tid; f < 64 * 16; f += 256) {
      const int t = f >> 4, c = f & 15;
      const int gt = t0 + t;
      dt_s[t][c] = dt[gt * D_INNER + d0 + c];
      xb_s[t][c] = xbc[gt * D_INNER + d0 + c];
      z_s[t][c] = xz[gt * (2 * D_INNER) + D_INNER + d0 + c];
      B_s[t][c] = xdbl[gt * 80 + DT_RANK + c];
      C_s[t][c] = xdbl[gt * 80 + DT_RANK + D_STATE + c];
    }
    __syncthreads();

    for (int t = 0; t < 64; ++t) {
      const float sdt = dt_s[t][ch];
      const float bx = xb_s[t][ch];
      const float dA = __expf(sdt * Aval);
      h = fmaf(dA, h, sdt * B_s[t][n] * bx);
      float p = h * C_s[t][n];
      p += __shfl_xor(p, 1, 16);
      p += __shfl_xor(p, 2, 16);
      p += __shfl_xor(p, 4, 16);
      p += __shfl_xor(p, 8, 16);
      if (n == 0) {
        const float zz = z_s[t][ch];
        const float sig = 1.f / (1.f + __expf(-zz));
        y_s[t][ch] = (p + bx * Dval) * (zz * sig);
      }
    }
    __syncthreads();

    for (int f = tid; f < 64 * 16; f += 256) {
      const int t = f >> 4, c = f & 15;
      ym[(t0 + t) * D_INNER + d0 + c] = y_s[t][c];
    }
    __syncthreads();
  }
}

// ---------------------------------------------------------------------------
extern "C" void kernel_launch(void* const* d_in, const int* in_sizes, int n_in,
                              void* d_out, int out_size, void* d_ws,
                              size_t ws_size, hipStream_t stream) {
  const float* x = (const float*)d_in[0];       // (2048, 768)
  const float* W_in = (const float*)d_in[1];    // (3072, 768)
  const float* conv_w = (const float*)d_in[2];  // (1536, 1, 4)
  const float* conv_b = (const float*)d_in[3];  // (1536,)
  const float* W_x = (const float*)d_in[4];     // (80, 1536)
  const float* W_dt = (const float*)d_in[5];    // (1536, 48)
  const float* b_dt = (const float*)d_in[6];    // (1536,)
  const float* A_log = (const float*)d_in[7];   // (1536, 16)
  const float* D_param = (const float*)d_in[8]; // (1536,)
  const float* W_out = (const float*)d_in[9];   // (768, 1536)
  float* out = (float*)d_out;                   // (2048, 768)

  float* ws = (float*)d_ws;
  float* xz = ws;                          // 2048*3072
  float* xbc = xz + SEQ * 2 * D_INNER;     // 2048*1536
  float* xdbl = xbc + SEQ * D_INNER;       // 2048*80
  float* dtb = xdbl + SEQ * 80;            // 2048*1536
  float* ym = dtb + SEQ * D_INNER;         // 2048*1536

  const dim3 blk(256);

  // xz = x @ W_in^T   (2048 x 3072), MFMA bf16-split, 24x16 = 384 blocks
  gemm_mfma_split<128, 128><<<dim3(2 * D_INNER / 128, SEQ / 128), blk, 0, stream>>>(
      x, D_MODEL, W_in, D_MODEL, xz, 2 * D_INNER, D_MODEL);

  // xbc = silu(causal_conv(xb) + conv_b)
  conv_silu_kernel<<<dim3(SEQ * D_INNER / 256), blk, 0, stream>>>(
      xz, conv_w, conv_b, xbc);

  // xdbl = xbc @ W_x^T   (2048 x 80), fp32
  gemm_kernel<0><<<dim3(2, SEQ / 64), blk, 0, stream>>>(
      xbc, D_INNER, W_x, D_INNER, nullptr, xdbl, 80, SEQ, 80, D_INNER);

  // dtb = softplus(xdbl[:, :48] @ W_dt^T + b_dt)   (2048 x 1536), fp32
  gemm_kernel<1><<<dim3(D_INNER / 64, SEQ / 64), blk, 0, stream>>>(
      xdbl, 80, W_dt, DT_RANK, b_dt, dtb, D_INNER, SEQ, D_INNER, DT_RANK);

  // ym = scan(...) fused
  scan_kernel<<<dim3(D_INNER / 16), blk, 0, stream>>>(
      dtb, xdbl, xbc, xz, A_log, D_param, ym);

  // out = ym @ W_out^T   (2048 x 768), MFMA bf16-split, 12x32 = 384 blocks
  gemm_mfma_split<64, 64><<<dim3(D_MODEL / 64, SEQ / 64), blk, 0, stream>>>(
      ym, D_INNER, W_out, D_INNER, out, D_MODEL, D_INNER);
}

// Round 6
// 413.534 us; speedup vs baseline: 2.2522x; 2.2522x over previous
//
#include <hip/hip_runtime.h>
#include <hip/hip_bf16.h>

#define D_MODEL 768
#define D_INNER 1536
#define D_STATE 16
#define DT_RANK 48
#define SEQ 2048
#define NC 32            // scan chunks
#define LC (SEQ / NC)    // 64 timesteps per chunk
#define DN (D_INNER * D_STATE)  // 24576 (d,n) pairs

typedef float f32x4 __attribute__((ext_vector_type(4)));
typedef short bf16x8 __attribute__((ext_vector_type(8)));

// round-to-nearest-even fp32 -> bf16 bits
__device__ __forceinline__ ushort f2bf_bits(float f) {
  uint u = __float_as_uint(f);
  u += 0x7FFFu + ((u >> 16) & 1u);
  return (ushort)(u >> 16);
}
__device__ __forceinline__ float bf_bits2f(ushort b) {
  return __uint_as_float(((uint)b) << 16);
}

// ---------------------------------------------------------------------------
// Elementwise fp32 -> (hi, lo) bf16 split. n must be a multiple of 1024.
// ---------------------------------------------------------------------------
__global__ __launch_bounds__(256) void split_bf16_kernel(
    const float* __restrict__ src, ushort* __restrict__ hi,
    ushort* __restrict__ lo) {
  const int idx = blockIdx.x * 256 + threadIdx.x;  // vec4 index
  const float4 v = ((const float4*)src)[idx];
  const float f[4] = {v.x, v.y, v.z, v.w};
  ushort4 h, l;
  ushort* hp = (ushort*)&h;
  ushort* lp = (ushort*)&l;
#pragma unroll
  for (int j = 0; j < 4; ++j) {
    const ushort hb = f2bf_bits(f[j]);
    hp[j] = hb;
    lp[j] = f2bf_bits(f[j] - bf_bits2f(hb));
  }
  ((ushort4*)hi)[idx] = h;
  ((ushort4*)lo)[idx] = l;
}

// ---------------------------------------------------------------------------
// MFMA GEMM on pre-split bf16 hi/lo operands.
// C = Ahi·Bhi^T + Ahi·Blo^T + Alo·Bhi^T   (3-term Ootomo split)
// A* (M,K) ushort row-major, B* (N,K) ushort row-major, C (M,N) fp32.
// 256 threads = 4 waves in 2x2. BK=64. M%BM==0, N%BN==0, K%64==0.
// LDS rows padded to 72 ushorts (144B) -> frag ds_read_b128 conflict-free.
// ---------------------------------------------------------------------------
template <int BM, int BN>
__global__ __launch_bounds__(256) void gemm_mfma_presplit(
    const ushort* __restrict__ Ah, const ushort* __restrict__ Al, int lda,
    const ushort* __restrict__ Bh, const ushort* __restrict__ Bl, int ldb,
    float* __restrict__ C, int ldc, int K) {
  __shared__ __align__(16) ushort As_hi[BM][72];
  __shared__ __align__(16) ushort As_lo[BM][72];
  __shared__ __align__(16) ushort Bs_hi[BN][72];
  __shared__ __align__(16) ushort Bs_lo[BN][72];

  const int tid = threadIdx.x;
  const int lane = tid & 63;
  const int wave = tid >> 6;
  const int m0 = blockIdx.y * BM;
  const int n0 = blockIdx.x * BN;

  constexpr int FM = BM / 32;
  constexpr int FN = BN / 32;
  const int wm0 = (wave >> 1) * (BM / 2);
  const int wn0 = (wave & 1) * (BN / 2);
  const int fr = lane & 15;
  const int kg = lane >> 4;

  f32x4 acc[FM][FN] = {};

  for (int k0 = 0; k0 < K; k0 += 64) {
    // ---- stage: pure 16B copies, no conversion ----
#pragma unroll
    for (int i = 0; i < BM * 64 / (256 * 8); ++i) {
      const int s = i * 256 + tid;
      const int row = s >> 3;          // 8 x uint4 per 64-elem row
      const int c8 = (s & 7) << 3;
      const size_t g = (size_t)(m0 + row) * lda + k0 + c8;
      *(uint4*)&As_hi[row][c8] = *(const uint4*)&Ah[g];
      *(uint4*)&As_lo[row][c8] = *(const uint4*)&Al[g];
    }
#pragma unroll
    for (int i = 0; i < BN * 64 / (256 * 8); ++i) {
      const int s = i * 256 + tid;
      const int row = s >> 3;
      const int c8 = (s & 7) << 3;
      const size_t g = (size_t)(n0 + row) * ldb + k0 + c8;
      *(uint4*)&Bs_hi[row][c8] = *(const uint4*)&Bh[g];
      *(uint4*)&Bs_lo[row][c8] = *(const uint4*)&Bl[g];
    }
    __syncthreads();

#pragma unroll
    for (int k2 = 0; k2 < 64; k2 += 32) {
      bf16x8 ah[FM], al[FM];
#pragma unroll
      for (int m = 0; m < FM; ++m) {
        ah[m] = *(const bf16x8*)&As_hi[wm0 + m * 16 + fr][k2 + kg * 8];
        al[m] = *(const bf16x8*)&As_lo[wm0 + m * 16 + fr][k2 + kg * 8];
      }
#pragma unroll
      for (int n = 0; n < FN; ++n) {
        const bf16x8 bh = *(const bf16x8*)&Bs_hi[wn0 + n * 16 + fr][k2 + kg * 8];
        const bf16x8 bl = *(const bf16x8*)&Bs_lo[wn0 + n * 16 + fr][k2 + kg * 8];
#pragma unroll
        for (int m = 0; m < FM; ++m) {
          acc[m][n] = __builtin_amdgcn_mfma_f32_16x16x32_bf16(ah[m], bh, acc[m][n], 0, 0, 0);
          acc[m][n] = __builtin_amdgcn_mfma_f32_16x16x32_bf16(ah[m], bl, acc[m][n], 0, 0, 0);
          acc[m][n] = __builtin_amdgcn_mfma_f32_16x16x32_bf16(al[m], bh, acc[m][n], 0, 0, 0);
        }
      }
    }
    __syncthreads();
  }

  // C/D layout: col = lane&15, row = (lane>>4)*4 + reg   [m89]
#pragma unroll
  for (int m = 0; m < FM; ++m) {
#pragma unroll
    for (int n = 0; n < FN; ++n) {
      const int row = m0 + wm0 + m * 16 + (lane >> 4) * 4;
      const int col = n0 + wn0 + n * 16 + (lane & 15);
#pragma unroll
      for (int r = 0; r < 4; ++r) C[(row + r) * ldc + col] = acc[m][n][r];
    }
  }
}

// ---------------------------------------------------------------------------
// fp32 fallback GEMM (small GEMMs): C = f(A @ B^T [+ bias])
// MODE 0: plain. MODE 1: softplus(acc + bias[n]). 64x64 tile, BK=16.
// ---------------------------------------------------------------------------
template <int MODE>
__global__ __launch_bounds__(256) void gemm_kernel(
    const float* __restrict__ A, int lda,
    const float* __restrict__ B, int ldb,
    const float* __restrict__ bias,
    float* __restrict__ C, int ldc,
    int M, int N, int K) {
  __shared__ __align__(16) float As[16][68];
  __shared__ __align__(16) float Bs[16][68];

  const int tid = threadIdx.x;
  const int tx = tid & 15;
  const int ty = tid >> 4;
  const int m0 = blockIdx.y * 64;
  const int n0 = blockIdx.x * 64;

  const int am = tid >> 2;
  const int ak = (tid & 3) << 2;

  float acc[4][4] = {};

  for (int k0 = 0; k0 < K; k0 += 16) {
    {
      const float4 av = *(const float4*)&A[(m0 + am) * lda + k0 + ak];
      As[ak + 0][am] = av.x;
      As[ak + 1][am] = av.y;
      As[ak + 2][am] = av.z;
      As[ak + 3][am] = av.w;
    }
    {
      const int bn = n0 + am;
      float4 bv = make_float4(0.f, 0.f, 0.f, 0.f);
      if (bn < N) bv = *(const float4*)&B[bn * ldb + k0 + ak];
      Bs[ak + 0][am] = bv.x;
      Bs[ak + 1][am] = bv.y;
      Bs[ak + 2][am] = bv.z;
      Bs[ak + 3][am] = bv.w;
    }
    __syncthreads();

#pragma unroll
    for (int k = 0; k < 16; ++k) {
      const float4 a = *(const float4*)&As[k][ty * 4];
      const float4 b = *(const float4*)&Bs[k][tx * 4];
      const float ar[4] = {a.x, a.y, a.z, a.w};
      const float br[4] = {b.x, b.y, b.z, b.w};
#pragma unroll
      for (int i = 0; i < 4; ++i)
#pragma unroll
        for (int j = 0; j < 4; ++j) acc[i][j] = fmaf(ar[i], br[j], acc[i][j]);
    }
    __syncthreads();
  }

#pragma unroll
  for (int i = 0; i < 4; ++i) {
    const int m = m0 + ty * 4 + i;
#pragma unroll
    for (int j = 0; j < 4; ++j) {
      const int n = n0 + tx * 4 + j;
      if (n < N) {
        float v = acc[i][j];
        if (MODE == 1) {
          v += bias[n];
          v = (v > 20.f) ? v : log1pf(__expf(v));  // softplus
        }
        C[m * ldc + n] = v;
      }
    }
  }
}

// ---------------------------------------------------------------------------
// Depthwise causal conv (width 4) + bias + SiLU.
// ---------------------------------------------------------------------------
__global__ __launch_bounds__(256) void conv_silu_kernel(
    const float* __restrict__ xz, const float* __restrict__ cw,
    const float* __restrict__ cb, float* __restrict__ xbc) {
  const int idx = blockIdx.x * 256 + threadIdx.x;
  const int t = idx / D_INNER;
  const int d = idx - t * D_INNER;
  float acc = cb[d];
#pragma unroll
  for (int j = 0; j < 4; ++j) {
    const int tt = t + j - 3;
    if (tt >= 0) acc = fmaf(xz[tt * (2 * D_INNER) + d], cw[d * 4 + j], acc);
  }
  xbc[idx] = acc / (1.f + __expf(-acc));  // silu
}

// ---------------------------------------------------------------------------
// Chunked selective scan, phase 1: per (chunk, d-group) local scan from h=0.
// Grid: (96 d-groups, NC chunks). Block: 256 = 16 ch x 16 n.
// ---------------------------------------------------------------------------
__global__ __launch_bounds__(256) void scan_part1(
    const float* __restrict__ dt, const float* __restrict__ xdbl,
    const float* __restrict__ xbc, const float* __restrict__ A_log,
    float* __restrict__ aprod, float* __restrict__ hloc) {
  __shared__ float dt_s[LC][16];
  __shared__ float xb_s[LC][16];
  __shared__ float B_s[LC][16];

  const int tid = threadIdx.x;
  const int ch = tid >> 4;
  const int n = tid & 15;
  const int d0 = blockIdx.x * 16;
  const int c = blockIdx.y;
  const int t0 = c * LC;

  for (int f = tid; f < LC * 16; f += 256) {
    const int t = f >> 4, cc = f & 15;
    const int gt = t0 + t;
    dt_s[t][cc] = dt[gt * D_INNER + d0 + cc];
    xb_s[t][cc] = xbc[gt * D_INNER + d0 + cc];
    B_s[t][cc] = xdbl[gt * 80 + DT_RANK + cc];
  }
  __syncthreads();

  const float Aval = -__expf(A_log[(d0 + ch) * D_STATE + n]);
  float h = 0.f, ap = 1.f;
#pragma unroll 4
  for (int t = 0; t < LC; ++t) {
    const float sdt = dt_s[t][ch];
    const float dA = __expf(sdt * Aval);
    h = fmaf(dA, h, sdt * B_s[t][n] * xb_s[t][ch]);
    ap *= dA;
  }
  const int idx = c * DN + d0 * 16 + tid;  // (d0+ch)*16+n == d0*16+tid
  aprod[idx] = ap;
  hloc[idx] = h;
}

// ---------------------------------------------------------------------------
// Phase 2: sequential combine over the NC chunk summaries per (d,n).
// ---------------------------------------------------------------------------
__global__ __launch_bounds__(256) void scan_combine(
    const float* __restrict__ aprod, const float* __restrict__ hloc,
    float* __restrict__ hstart) {
  const int idx = blockIdx.x * 256 + threadIdx.x;  // < DN
  float hs = 0.f;
#pragma unroll
  for (int c = 0; c < NC; ++c) {
    const float a = aprod[c * DN + idx];
    const float hl = hloc[c * DN + idx];
    hstart[c * DN + idx] = hs;
    hs = fmaf(a, hs, hl);
  }
}

// ---------------------------------------------------------------------------
// Phase 3: re-scan each chunk from its true h_start; fused +xbc*D, *silu(z)
// epilogue; writes ym directly as pre-split bf16 hi/lo for GEMM4.
// ---------------------------------------------------------------------------
__global__ __launch_bounds__(256) void scan_part3(
    const float* __restrict__ dt, const float* __restrict__ xdbl,
    const float* __restrict__ xbc, const float* __restrict__ xz,
    const float* __restrict__ A_log, const float* __restrict__ Dp,
    const float* __restrict__ hstart,
    ushort* __restrict__ ym_hi, ushort* __restrict__ ym_lo) {
  __shared__ float dt_s[LC][16];
  __shared__ float xb_s[LC][16];
  __shared__ float z_s[LC][16];
  __shared__ float B_s[LC][16];
  __shared__ float C_s[LC][16];
  __shared__ float y_s[LC][16];

  const int tid = threadIdx.x;
  const int ch = tid >> 4;
  const int n = tid & 15;
  const int d0 = blockIdx.x * 16;
  const int c = blockIdx.y;
  const int t0 = c * LC;

  for (int f = tid; f < LC * 16; f += 256) {
    const int t = f >> 4, cc = f & 15;
    const int gt = t0 + t;
    dt_s[t][cc] = dt[gt * D_INNER + d0 + cc];
    xb_s[t][cc] = xbc[gt * D_INNER + d0 + cc];
    z_s[t][cc] = xz[gt * (2 * D_INNER) + D_INNER + d0 + cc];
    B_s[t][cc] = xdbl[gt * 80 + DT_RANK + cc];
    C_s[t][cc] = xdbl[gt * 80 + DT_RANK + D_STATE + cc];
  }
  __syncthreads();

  const float Aval = -__expf(A_log[(d0 + ch) * D_STATE + n]);
  const float Dval = Dp[d0 + ch];
  float h = hstart[c * DN + d0 * 16 + tid];

#pragma unroll 4
  for (int t = 0; t < LC; ++t) {
    const float sdt = dt_s[t][ch];
    const float bx = xb_s[t][ch];
    const float dA = __expf(sdt * Aval);
    h = fmaf(dA, h, sdt * B_s[t][n] * bx);
    float p = h * C_s[t][n];
    p += __shfl_xor(p, 1, 16);
    p += __shfl_xor(p, 2, 16);
    p += __shfl_xor(p, 4, 16);
    p += __shfl_xor(p, 8, 16);
    if (n == 0) {
      const float zz = z_s[t][ch];
      const float sig = 1.f / (1.f + __expf(-zz));
      y_s[t][ch] = (p + bx * Dval) * (zz * sig);
    }
  }
  __syncthreads();

  for (int f = tid; f < LC * 16; f += 256) {
    const int t = f >> 4, cc = f & 15;
    const float v = y_s[t][cc];
    const ushort hb = f2bf_bits(v);
    const int gidx = (t0 + t) * D_INNER + d0 + cc;
    ym_hi[gidx] = hb;
    ym_lo[gidx] = f2bf_bits(v - bf_bits2f(hb));
  }
}

// ---------------------------------------------------------------------------
extern "C" void kernel_launch(void* const* d_in, const int* in_sizes, int n_in,
                              void* d_out, int out_size, void* d_ws,
                              size_t ws_size, hipStream_t stream) {
  const float* x = (const float*)d_in[0];       // (2048, 768)
  const float* W_in = (const float*)d_in[1];    // (3072, 768)
  const float* conv_w = (const float*)d_in[2];  // (1536, 1, 4)
  const float* conv_b = (const float*)d_in[3];  // (1536,)
  const float* W_x = (const float*)d_in[4];     // (80, 1536)
  const float* W_dt = (const float*)d_in[5];    // (1536, 48)
  const float* b_dt = (const float*)d_in[6];    // (1536,)
  const float* A_log = (const float*)d_in[7];   // (1536, 16)
  const float* D_param = (const float*)d_in[8]; // (1536,)
  const float* W_out = (const float*)d_in[9];   // (768, 1536)
  float* out = (float*)d_out;                   // (2048, 768)

  // ---- workspace layout (fp32 region, then bf16 hi/lo region) ----
  float* ws = (float*)d_ws;
  float* xz = ws;                            // 2048*3072
  float* xbc = xz + SEQ * 2 * D_INNER;       // 2048*1536
  float* xdbl = xbc + SEQ * D_INNER;         // 2048*80
  float* dtb = xdbl + SEQ * 80;              // 2048*1536
  float* aprod = dtb + SEQ * D_INNER;        // NC*DN
  float* hloc = aprod + NC * DN;             // NC*DN
  float* hstart = hloc + NC * DN;            // NC*DN

  ushort* x_hi = (ushort*)(hstart + NC * DN);       // 2048*768
  ushort* x_lo = x_hi + SEQ * D_MODEL;
  ushort* wi_hi = x_lo + SEQ * D_MODEL;             // 3072*768
  ushort* wi_lo = wi_hi + 2 * D_INNER * D_MODEL;
  ushort* wo_hi = wi_lo + 2 * D_INNER * D_MODEL;    // 768*1536
  ushort* wo_lo = wo_hi + D_MODEL * D_INNER;
  ushort* ym_hi = wo_lo + D_MODEL * D_INNER;        // 2048*1536
  ushort* ym_lo = ym_hi + SEQ * D_INNER;

  const dim3 blk(256);

  // ---- pre-split x, W_in, W_out into bf16 hi/lo ----
  split_bf16_kernel<<<dim3(SEQ * D_MODEL / 1024), blk, 0, stream>>>(x, x_hi, x_lo);
  split_bf16_kernel<<<dim3(2 * D_INNER * D_MODEL / 1024), blk, 0, stream>>>(W_in, wi_hi, wi_lo);
  split_bf16_kernel<<<dim3(D_MODEL * D_INNER / 1024), blk, 0, stream>>>(W_out, wo_hi, wo_lo);

  // xz = x @ W_in^T   (2048 x 3072), MFMA pre-split
  gemm_mfma_presplit<128, 128><<<dim3(2 * D_INNER / 128, SEQ / 128), blk, 0, stream>>>(
      x_hi, x_lo, D_MODEL, wi_hi, wi_lo, D_MODEL, xz, 2 * D_INNER, D_MODEL);

  // xbc = silu(causal_conv(xb) + conv_b)
  conv_silu_kernel<<<dim3(SEQ * D_INNER / 256), blk, 0, stream>>>(
      xz, conv_w, conv_b, xbc);

  // xdbl = xbc @ W_x^T   (2048 x 80), fp32
  gemm_kernel<0><<<dim3(2, SEQ / 64), blk, 0, stream>>>(
      xbc, D_INNER, W_x, D_INNER, nullptr, xdbl, 80, SEQ, 80, D_INNER);

  // dtb = softplus(xdbl[:, :48] @ W_dt^T + b_dt)   (2048 x 1536), fp32
  gemm_kernel<1><<<dim3(D_INNER / 64, SEQ / 64), blk, 0, stream>>>(
      xdbl, 80, W_dt, DT_RANK, b_dt, dtb, D_INNER, SEQ, D_INNER, DT_RANK);

  // chunked scan: local scans -> combine -> finalize (writes ym as hi/lo)
  scan_part1<<<dim3(D_INNER / 16, NC), blk, 0, stream>>>(
      dtb, xdbl, xbc, A_log, aprod, hloc);
  scan_combine<<<dim3(DN / 256), blk, 0, stream>>>(aprod, hloc, hstart);
  scan_part3<<<dim3(D_INNER / 16, NC), blk, 0, stream>>>(
      dtb, xdbl, xbc, xz, A_log, D_param, hstart, ym_hi, ym_lo);

  // out = ym @ W_out^T   (2048 x 768), MFMA pre-split
  gemm_mfma_presplit<64, 64><<<dim3(D_MODEL / 64, SEQ / 64), blk, 0, stream>>>(
      ym_hi, ym_lo, D_INNER, wo_hi, wo_lo, D_INNER, out, D_MODEL, D_INNER);
}

// Round 8
// 341.677 us; speedup vs baseline: 2.7259x; 1.2103x over previous
//
#include <hip/hip_runtime.h>
#include <hip/hip_bf16.h>

#define D_MODEL 768
#define D_INNER 1536
#define D_STATE 16
#define DT_RANK 48
#define SEQ 2048
#define NC 32            // scan chunks
#define LC (SEQ / NC)    // 64 timesteps per chunk
#define DN (D_INNER * D_STATE)  // 24576 (d,n) pairs
#define KS 8             // GEMM2 split-K ways
#define KCH (D_INNER / KS)  // 192

typedef float f32x4 __attribute__((ext_vector_type(4)));
typedef short bf16x8 __attribute__((ext_vector_type(8)));

// round-to-nearest-even fp32 -> bf16 bits
__device__ __forceinline__ ushort f2bf_bits(float f) {
  uint u = __float_as_uint(f);
  u += 0x7FFFu + ((u >> 16) & 1u);
  return (ushort)(u >> 16);
}
__device__ __forceinline__ float bf_bits2f(ushort b) {
  return __uint_as_float(((uint)b) << 16);
}

__device__ __forceinline__ void split_vec4(const float* __restrict__ src,
                                           ushort* __restrict__ hi,
                                           ushort* __restrict__ lo, int idx) {
  const float4 v = ((const float4*)src)[idx];
  const float f[4] = {v.x, v.y, v.z, v.w};
  ushort4 h, l;
  ushort* hp = (ushort*)&h;
  ushort* lp = (ushort*)&l;
#pragma unroll
  for (int j = 0; j < 4; ++j) {
    const ushort hb = f2bf_bits(f[j]);
    hp[j] = hb;
    lp[j] = f2bf_bits(f[j] - bf_bits2f(hb));
  }
  ((ushort4*)hi)[idx] = h;
  ((ushort4*)lo)[idx] = l;
}

// ---------------------------------------------------------------------------
// Fused fp32 -> (hi,lo) bf16 split of three tensors (x, W_in, W_out).
// Grid covers n0v+n1v+n2v vec4 elements, segmented by blockIdx range.
// ---------------------------------------------------------------------------
__global__ __launch_bounds__(256) void split3_bf16_kernel(
    const float* __restrict__ s0, ushort* __restrict__ h0, ushort* __restrict__ l0, int n0v,
    const float* __restrict__ s1, ushort* __restrict__ h1, ushort* __restrict__ l1, int n1v,
    const float* __restrict__ s2, ushort* __restrict__ h2, ushort* __restrict__ l2) {
  int idx = blockIdx.x * 256 + threadIdx.x;
  if (idx < n0v) {
    split_vec4(s0, h0, l0, idx);
  } else if (idx < n0v + n1v) {
    split_vec4(s1, h1, l1, idx - n0v);
  } else {
    split_vec4(s2, h2, l2, idx - n0v - n1v);
  }
}

// ---------------------------------------------------------------------------
// MFMA GEMM on pre-split bf16 hi/lo operands.
// C = Ahi·Bhi^T + Ahi·Blo^T + Alo·Bhi^T   (3-term Ootomo split)
// A* (M,K) ushort row-major, B* (N,K) ushort row-major, C (M,N) fp32.
// 256 threads = 4 waves in 2x2. BK=64. M%BM==0, N%BN==0, K%64==0.
// LDS rows padded to 72 ushorts (144B) -> frag ds_read_b128 ~conflict-free.
// ---------------------------------------------------------------------------
template <int BM, int BN>
__global__ __launch_bounds__(256) void gemm_mfma_presplit(
    const ushort* __restrict__ Ah, const ushort* __restrict__ Al, int lda,
    const ushort* __restrict__ Bh, const ushort* __restrict__ Bl, int ldb,
    float* __restrict__ C, int ldc, int K) {
  __shared__ __align__(16) ushort As_hi[BM][72];
  __shared__ __align__(16) ushort As_lo[BM][72];
  __shared__ __align__(16) ushort Bs_hi[BN][72];
  __shared__ __align__(16) ushort Bs_lo[BN][72];

  const int tid = threadIdx.x;
  const int lane = tid & 63;
  const int wave = tid >> 6;
  const int m0 = blockIdx.y * BM;
  const int n0 = blockIdx.x * BN;

  constexpr int FM = BM / 32;
  constexpr int FN = BN / 32;
  const int wm0 = (wave >> 1) * (BM / 2);
  const int wn0 = (wave & 1) * (BN / 2);
  const int fr = lane & 15;
  const int kg = lane >> 4;

  f32x4 acc[FM][FN] = {};

  for (int k0 = 0; k0 < K; k0 += 64) {
    // ---- stage: pure 16B copies, no conversion ----
#pragma unroll
    for (int i = 0; i < BM * 64 / (256 * 8); ++i) {
      const int s = i * 256 + tid;
      const int row = s >> 3;          // 8 x uint4 per 64-elem row
      const int c8 = (s & 7) << 3;
      const size_t g = (size_t)(m0 + row) * lda + k0 + c8;
      *(uint4*)&As_hi[row][c8] = *(const uint4*)&Ah[g];
      *(uint4*)&As_lo[row][c8] = *(const uint4*)&Al[g];
    }
#pragma unroll
    for (int i = 0; i < BN * 64 / (256 * 8); ++i) {
      const int s = i * 256 + tid;
      const int row = s >> 3;
      const int c8 = (s & 7) << 3;
      const size_t g = (size_t)(n0 + row) * ldb + k0 + c8;
      *(uint4*)&Bs_hi[row][c8] = *(const uint4*)&Bh[g];
      *(uint4*)&Bs_lo[row][c8] = *(const uint4*)&Bl[g];
    }
    __syncthreads();

#pragma unroll
    for (int k2 = 0; k2 < 64; k2 += 32) {
      bf16x8 ah[FM], al[FM];
#pragma unroll
      for (int m = 0; m < FM; ++m) {
        ah[m] = *(const bf16x8*)&As_hi[wm0 + m * 16 + fr][k2 + kg * 8];
        al[m] = *(const bf16x8*)&As_lo[wm0 + m * 16 + fr][k2 + kg * 8];
      }
#pragma unroll
      for (int n = 0; n < FN; ++n) {
        const bf16x8 bh = *(const bf16x8*)&Bs_hi[wn0 + n * 16 + fr][k2 + kg * 8];
        const bf16x8 bl = *(const bf16x8*)&Bs_lo[wn0 + n * 16 + fr][k2 + kg * 8];
#pragma unroll
        for (int m = 0; m < FM; ++m) {
          acc[m][n] = __builtin_amdgcn_mfma_f32_16x16x32_bf16(ah[m], bh, acc[m][n], 0, 0, 0);
          acc[m][n] = __builtin_amdgcn_mfma_f32_16x16x32_bf16(ah[m], bl, acc[m][n], 0, 0, 0);
          acc[m][n] = __builtin_amdgcn_mfma_f32_16x16x32_bf16(al[m], bh, acc[m][n], 0, 0, 0);
        }
      }
    }
    __syncthreads();
  }

  // C/D layout: col = lane&15, row = (lane>>4)*4 + reg   [m89]
#pragma unroll
  for (int m = 0; m < FM; ++m) {
#pragma unroll
    for (int n = 0; n < FN; ++n) {
      const int row = m0 + wm0 + m * 16 + (lane >> 4) * 4;
      const int col = n0 + wn0 + n * 16 + (lane & 15);
#pragma unroll
      for (int r = 0; r < 4; ++r) C[(row + r) * ldc + col] = acc[m][n][r];
    }
  }
}

// ---------------------------------------------------------------------------
// GEMM2 split-K: part[ks] = xbc[:, ks*192:(ks+1)*192] @ W_x[:, same]^T
// Grid (SEQ/64, KS). Block 256 = 16x16; 4x5 micro-tile (N=80 = 16 cols x 5).
// ---------------------------------------------------------------------------
__global__ __launch_bounds__(256) void gemm2_splitk(
    const float* __restrict__ A,   // xbc (SEQ, D_INNER)
    const float* __restrict__ B,   // W_x (80, D_INNER)
    float* __restrict__ part) {    // (KS, SEQ, 80)
  __shared__ __align__(16) float As[16][68];
  __shared__ __align__(16) float Bs[16][84];

  const int tid = threadIdx.x;
  const int tx = tid & 15;
  const int ty = tid >> 4;
  const int m0 = blockIdx.x * 64;
  const int kbase = blockIdx.y * KCH;

  float acc[4][5] = {};

  for (int k0 = 0; k0 < KCH; k0 += 16) {
    {  // stage A 64x16
      const int am = tid >> 2;
      const int ak = (tid & 3) << 2;
      const float4 av = *(const float4*)&A[(m0 + am) * D_INNER + kbase + k0 + ak];
      As[ak + 0][am] = av.x;
      As[ak + 1][am] = av.y;
      As[ak + 2][am] = av.z;
      As[ak + 3][am] = av.w;
    }
    // stage B 80x16
    for (int f = tid; f < 80 * 4; f += 256) {
      const int row = f >> 2;
      const int kk = (f & 3) << 2;
      const float4 bv = *(const float4*)&B[row * D_INNER + kbase + k0 + kk];
      Bs[kk + 0][row] = bv.x;
      Bs[kk + 1][row] = bv.y;
      Bs[kk + 2][row] = bv.z;
      Bs[kk + 3][row] = bv.w;
    }
    __syncthreads();

#pragma unroll
    for (int k = 0; k < 16; ++k) {
      const float4 a4 = *(const float4*)&As[k][ty * 4];
      const float a[4] = {a4.x, a4.y, a4.z, a4.w};
      float b[5];
#pragma unroll
      for (int j = 0; j < 5; ++j) b[j] = Bs[k][tx + 16 * j];
#pragma unroll
      for (int i = 0; i < 4; ++i)
#pragma unroll
        for (int j = 0; j < 5; ++j) acc[i][j] = fmaf(a[i], b[j], acc[i][j]);
    }
    __syncthreads();
  }

  const int pb = (blockIdx.y * SEQ + m0) * 80;
#pragma unroll
  for (int i = 0; i < 4; ++i)
#pragma unroll
    for (int j = 0; j < 5; ++j)
      part[pb + (ty * 4 + i) * 80 + tx + 16 * j] = acc[i][j];
}

__global__ __launch_bounds__(256) void gemm2_reduce(
    const float* __restrict__ part, float* __restrict__ xdbl) {
  const int idx = blockIdx.x * 256 + threadIdx.x;  // < SEQ*80
  float s = 0.f;
#pragma unroll
  for (int ks = 0; ks < KS; ++ks) s += part[ks * SEQ * 80 + idx];
  xdbl[idx] = s;
}

// ---------------------------------------------------------------------------
// fp32 GEMM (GEMM3 only): C = softplus(A @ B^T + bias). 64x64 tile, BK=16.
// ---------------------------------------------------------------------------
template <int MODE>
__global__ __launch_bounds__(256) void gemm_kernel(
    const float* __restrict__ A, int lda,
    const float* __restrict__ B, int ldb,
    const float* __restrict__ bias,
    float* __restrict__ C, int ldc,
    int M, int N, int K) {
  __shared__ __align__(16) float As[16][68];
  __shared__ __align__(16) float Bs[16][68];

  const int tid = threadIdx.x;
  const int tx = tid & 15;
  const int ty = tid >> 4;
  const int m0 = blockIdx.y * 64;
  const int n0 = blockIdx.x * 64;

  const int am = tid >> 2;
  const int ak = (tid & 3) << 2;

  float acc[4][4] = {};

  for (int k0 = 0; k0 < K; k0 += 16) {
    {
      const float4 av = *(const float4*)&A[(m0 + am) * lda + k0 + ak];
      As[ak + 0][am] = av.x;
      As[ak + 1][am] = av.y;
      As[ak + 2][am] = av.z;
      As[ak + 3][am] = av.w;
    }
    {
      const int bn = n0 + am;
      float4 bv = make_float4(0.f, 0.f, 0.f, 0.f);
      if (bn < N) bv = *(const float4*)&B[bn * ldb + k0 + ak];
      Bs[ak + 0][am] = bv.x;
      Bs[ak + 1][am] = bv.y;
      Bs[ak + 2][am] = bv.z;
      Bs[ak + 3][am] = bv.w;
    }
    __syncthreads();

#pragma unroll
    for (int k = 0; k < 16; ++k) {
      const float4 a = *(const float4*)&As[k][ty * 4];
      const float4 b = *(const float4*)&Bs[k][tx * 4];
      const float ar[4] = {a.x, a.y, a.z, a.w};
      const float br[4] = {b.x, b.y, b.z, b.w};
#pragma unroll
      for (int i = 0; i < 4; ++i)
#pragma unroll
        for (int j = 0; j < 4; ++j) acc[i][j] = fmaf(ar[i], br[j], acc[i][j]);
    }
    __syncthreads();
  }

#pragma unroll
  for (int i = 0; i < 4; ++i) {
    const int m = m0 + ty * 4 + i;
#pragma unroll
    for (int j = 0; j < 4; ++j) {
      const int n = n0 + tx * 4 + j;
      if (n < N) {
        float v = acc[i][j];
        if (MODE == 1) {
          v += bias[n];
          v = (v > 20.f) ? v : log1pf(__expf(v));  // softplus
        }
        C[m * ldc + n] = v;
      }
    }
  }
}

// ---------------------------------------------------------------------------
// Depthwise causal conv (width 4) + bias + SiLU, vectorized x4 channels.
// ---------------------------------------------------------------------------
__global__ __launch_bounds__(256) void conv_silu_kernel(
    const float* __restrict__ xz, const float* __restrict__ cw,
    const float* __restrict__ cb, float* __restrict__ xbc) {
  const int idx = blockIdx.x * 256 + threadIdx.x;  // < SEQ * D_INNER/4
  const int t = idx / (D_INNER / 4);
  const int d = (idx - t * (D_INNER / 4)) * 4;
  // all 4 taps for 4 consecutive channels
  const float4 w0 = *(const float4*)&cw[(d + 0) * 4];
  const float4 w1 = *(const float4*)&cw[(d + 1) * 4];
  const float4 w2 = *(const float4*)&cw[(d + 2) * 4];
  const float4 w3 = *(const float4*)&cw[(d + 3) * 4];
  float4 acc = *(const float4*)&cb[d];
#pragma unroll
  for (int j = 0; j < 4; ++j) {
    const int tt = t + j - 3;
    if (tt >= 0) {
      const float4 xv = *(const float4*)&xz[tt * (2 * D_INNER) + d];
      acc.x = fmaf(xv.x, ((const float*)&w0)[j], acc.x);
      acc.y = fmaf(xv.y, ((const float*)&w1)[j], acc.y);
      acc.z = fmaf(xv.z, ((const float*)&w2)[j], acc.z);
      acc.w = fmaf(xv.w, ((const float*)&w3)[j], acc.w);
    }
  }
  float4 r;
  r.x = acc.x / (1.f + __expf(-acc.x));
  r.y = acc.y / (1.f + __expf(-acc.y));
  r.z = acc.z / (1.f + __expf(-acc.z));
  r.w = acc.w / (1.f + __expf(-acc.w));
  *(float4*)&xbc[t * D_INNER + d] = r;
}

// ---------------------------------------------------------------------------
// Chunked selective scan, phase 1: per (chunk, d-group) local scan from h=0.
// ---------------------------------------------------------------------------
__global__ __launch_bounds__(256) void scan_part1(
    const float* __restrict__ dt, const float* __restrict__ xdbl,
    const float* __restrict__ xbc, const float* __restrict__ A_log,
    float* __restrict__ aprod, float* __restrict__ hloc) {
  __shared__ float dt_s[LC][16];
  __shared__ float xb_s[LC][16];
  __shared__ float B_s[LC][16];

  const int tid = threadIdx.x;
  const int ch = tid >> 4;
  const int n = tid & 15;
  const int d0 = blockIdx.x * 16;
  const int c = blockIdx.y;
  const int t0 = c * LC;

  for (int f = tid; f < LC * 16; f += 256) {
    const int t = f >> 4, cc = f & 15;
    const int gt = t0 + t;
    dt_s[t][cc] = dt[gt * D_INNER + d0 + cc];
    xb_s[t][cc] = xbc[gt * D_INNER + d0 + cc];
    B_s[t][cc] = xdbl[gt * 80 + DT_RANK + cc];
  }
  __syncthreads();

  const float Aval = -__expf(A_log[(d0 + ch) * D_STATE + n]);
  float h = 0.f, ap = 1.f;
#pragma unroll 4
  for (int t = 0; t < LC; ++t) {
    const float sdt = dt_s[t][ch];
    const float dA = __expf(sdt * Aval);
    h = fmaf(dA, h, sdt * B_s[t][n] * xb_s[t][ch]);
    ap *= dA;
  }
  const int idx = c * DN + d0 * 16 + tid;
  aprod[idx] = ap;
  hloc[idx] = h;
}

// ---------------------------------------------------------------------------
// Phase 2: sequential combine over the NC chunk summaries per (d,n).
// ---------------------------------------------------------------------------
__global__ __launch_bounds__(256) void scan_combine(
    const float* __restrict__ aprod, const float* __restrict__ hloc,
    float* __restrict__ hstart) {
  const int idx = blockIdx.x * 256 + threadIdx.x;  // < DN
  float hs = 0.f;
#pragma unroll
  for (int c = 0; c < NC; ++c) {
    const float a = aprod[c * DN + idx];
    const float hl = hloc[c * DN + idx];
    hstart[c * DN + idx] = hs;
    hs = fmaf(a, hs, hl);
  }
}

// ---------------------------------------------------------------------------
// Phase 3: re-scan each chunk from its true h_start; fused +xbc*D, *silu(z)
// epilogue; writes ym directly as pre-split bf16 hi/lo for GEMM4.
// ---------------------------------------------------------------------------
__global__ __launch_bounds__(256) void scan_part3(
    const float* __restrict__ dt, const float* __restrict__ xdbl,
    const float* __restrict__ xbc, const float* __restrict__ xz,
    const float* __restrict__ A_log, const float* __restrict__ Dp,
    const float* __restrict__ hstart,
    ushort* __restrict__ ym_hi, ushort* __restrict__ ym_lo) {
  __shared__ float dt_s[LC][16];
  __shared__ float xb_s[LC][16];
  __shared__ float z_s[LC][16];
  __shared__ float B_s[LC][16];
  __shared__ float C_s[LC][16];
  __shared__ float y_s[LC][16];

  const int tid = threadIdx.x;
  const int ch = tid >> 4;
  const int n = tid & 15;
  const int d0 = blockIdx.x * 16;
  const int c = blockIdx.y;
  const int t0 = c * LC;

  for (int f = tid; f < LC * 16; f += 256) {
    const int t = f >> 4, cc = f & 15;
    const int gt = t0 + t;
    dt_s[t][cc] = dt[gt * D_INNER + d0 + cc];
    xb_s[t][cc] = xbc[gt * D_INNER + d0 + cc];
    z_s[t][cc] = xz[gt * (2 * D_INNER) + D_INNER + d0 + cc];
    B_s[t][cc] = xdbl[gt * 80 + DT_RANK + cc];
    C_s[t][cc] = xdbl[gt * 80 + DT_RANK + D_STATE + cc];
  }
  __syncthreads();

  const float Aval = -__expf(A_log[(d0 + ch) * D_STATE + n]);
  const float Dval = Dp[d0 + ch];
  float h = hstart[c * DN + d0 * 16 + tid];

#pragma unroll 4
  for (int t = 0; t < LC; ++t) {
    const float sdt = dt_s[t][ch];
    const float bx = xb_s[t][ch];
    const float dA = __expf(sdt * Aval);
    h = fmaf(dA, h, sdt * B_s[t][n] * bx);
    float p = h * C_s[t][n];
    p += __shfl_xor(p, 1, 16);
    p += __shfl_xor(p, 2, 16);
    p += __shfl_xor(p, 4, 16);
    p += __shfl_xor(p, 8, 16);
    if (n == 0) {
      const float zz = z_s[t][ch];
      const float sig = 1.f / (1.f + __expf(-zz));
      y_s[t][ch] = (p + bx * Dval) * (zz * sig);
    }
  }
  __syncthreads();

  for (int f = tid; f < LC * 16; f += 256) {
    const int t = f >> 4, cc = f & 15;
    const float v = y_s[t][cc];
    const ushort hb = f2bf_bits(v);
    const int gidx = (t0 + t) * D_INNER + d0 + cc;
    ym_hi[gidx] = hb;
    ym_lo[gidx] = f2bf_bits(v - bf_bits2f(hb));
  }
}

// ---------------------------------------------------------------------------
extern "C" void kernel_launch(void* const* d_in, const int* in_sizes, int n_in,
                              void* d_out, int out_size, void* d_ws,
                              size_t ws_size, hipStream_t stream) {
  const float* x = (const float*)d_in[0];       // (2048, 768)
  const float* W_in = (const float*)d_in[1];    // (3072, 768)
  const float* conv_w = (const float*)d_in[2];  // (1536, 1, 4)
  const float* conv_b = (const float*)d_in[3];  // (1536,)
  const float* W_x = (const float*)d_in[4];     // (80, 1536)
  const float* W_dt = (const float*)d_in[5];    // (1536, 48)
  const float* b_dt = (const float*)d_in[6];    // (1536,)
  const float* A_log = (const float*)d_in[7];   // (1536, 16)
  const float* D_param = (const float*)d_in[8]; // (1536,)
  const float* W_out = (const float*)d_in[9];   // (768, 1536)
  float* out = (float*)d_out;                   // (2048, 768)

  // ---- workspace layout (fp32 region, then bf16 hi/lo region) ----
  float* ws = (float*)d_ws;
  float* xz = ws;                            // 2048*3072
  float* xbc = xz + SEQ * 2 * D_INNER;       // 2048*1536
  float* xdbl = xbc + SEQ * D_INNER;         // 2048*80
  float* dtb = xdbl + SEQ * 80;              // 2048*1536
  float* aprod = dtb + SEQ * D_INNER;        // NC*DN
  float* hloc = aprod + NC * DN;             // NC*DN
  float* hstart = hloc + NC * DN;            // NC*DN

  ushort* x_hi = (ushort*)(hstart + NC * DN);       // 2048*768
  ushort* x_lo = x_hi + SEQ * D_MODEL;
  ushort* wi_hi = x_lo + SEQ * D_MODEL;             // 3072*768
  ushort* wi_lo = wi_hi + 2 * D_INNER * D_MODEL;
  ushort* wo_hi = wi_lo + 2 * D_INNER * D_MODEL;    // 768*1536
  ushort* wo_lo = wo_hi + D_MODEL * D_INNER;
  ushort* ym_hi = wo_lo + D_MODEL * D_INNER;        // 2048*1536
  ushort* ym_lo = ym_hi + SEQ * D_INNER;

  // GEMM2 split-K partials (KS*SEQ*80 fp32 = 5.24 MB) alias the x_hi/x_lo
  // region (6.29 MB): x_hi/x_lo are dead once gemm_mfma_presplit<128,128>
  // (GEMM1) has completed, and gemm2_splitk runs strictly after it.
  float* part = (float*)x_hi;

  const dim3 blk(256);

  // ---- pre-split x, W_in, W_out into bf16 hi/lo (single fused launch) ----
  const int n0v = SEQ * D_MODEL / 4;            // 393216
  const int n1v = 2 * D_INNER * D_MODEL / 4;    // 589824
  const int n2v = D_MODEL * D_INNER / 4;        // 294912
  split3_bf16_kernel<<<dim3((n0v + n1v + n2v) / 256), blk, 0, stream>>>(
      x, x_hi, x_lo, n0v, W_in, wi_hi, wi_lo, n1v, W_out, wo_hi, wo_lo);

  // xz = x @ W_in^T   (2048 x 3072), MFMA pre-split
  gemm_mfma_presplit<128, 128><<<dim3(2 * D_INNER / 128, SEQ / 128), blk, 0, stream>>>(
      x_hi, x_lo, D_MODEL, wi_hi, wi_lo, D_MODEL, xz, 2 * D_INNER, D_MODEL);

  // xbc = silu(causal_conv(xb) + conv_b), x4 vectorized
  conv_silu_kernel<<<dim3(SEQ * D_INNER / 1024), blk, 0, stream>>>(
      xz, conv_w, conv_b, xbc);

  // xdbl = xbc @ W_x^T   (2048 x 80), 8-way split-K + reduce
  gemm2_splitk<<<dim3(SEQ / 64, KS), blk, 0, stream>>>(xbc, W_x, part);
  gemm2_reduce<<<dim3(SEQ * 80 / 256), blk, 0, stream>>>(part, xdbl);

  // dtb = softplus(xdbl[:, :48] @ W_dt^T + b_dt)   (2048 x 1536), fp32
  gemm_kernel<1><<<dim3(D_INNER / 64, SEQ / 64), blk, 0, stream>>>(
      xdbl, 80, W_dt, DT_RANK, b_dt, dtb, D_INNER, SEQ, D_INNER, DT_RANK);

  // chunked scan: local scans -> combine -> finalize (writes ym as hi/lo)
  scan_part1<<<dim3(D_INNER / 16, NC), blk, 0, stream>>>(
      dtb, xdbl, xbc, A_log, aprod, hloc);
  scan_combine<<<dim3(DN / 256), blk, 0, stream>>>(aprod, hloc, hstart);
  scan_part3<<<dim3(D_INNER / 16, NC), blk, 0, stream>>>(
      dtb, xdbl, xbc, xz, A_log, D_param, hstart, ym_hi, ym_lo);

  // out = ym @ W_out^T   (2048 x 768), MFMA pre-split
  gemm_mfma_presplit<64, 64><<<dim3(D_MODEL / 64, SEQ / 64), blk, 0, stream>>>(
      ym_hi, ym_lo, D_INNER, wo_hi, wo_lo, D_INNER, out, D_MODEL, D_INNER);
}

// Round 9
// 305.241 us; speedup vs baseline: 3.0513x; 1.1194x over previous
//
#include <hip/hip_runtime.h>
#include <hip/hip_bf16.h>

#define D_MODEL 768
#define D_INNER 1536
#define D_STATE 16
#define DT_RANK 48
#define SEQ 2048
#define NC 32            // scan chunks
#define LC (SEQ / NC)    // 64 timesteps per chunk
#define DN (D_INNER * D_STATE)  // 24576 (d,n) pairs
#define KS 8             // GEMM2 split-K ways
#define KCH (D_INNER / KS)  // 192

typedef float f32x4 __attribute__((ext_vector_type(4)));
typedef short bf16x8 __attribute__((ext_vector_type(8)));

typedef const __attribute__((address_space(1))) unsigned int* gas_u32;
typedef __attribute__((address_space(3))) unsigned int* las_u32;

// async global->LDS, 16B per lane; LDS dest = uniform base + lane*16 (m104)
__device__ __forceinline__ void gload16(const void* g, void* l) {
  __builtin_amdgcn_global_load_lds((gas_u32)g, (las_u32)l, 16, 0, 0);
}

// round-to-nearest-even fp32 -> bf16 bits
__device__ __forceinline__ ushort f2bf_bits(float f) {
  uint u = __float_as_uint(f);
  u += 0x7FFFu + ((u >> 16) & 1u);
  return (ushort)(u >> 16);
}
__device__ __forceinline__ float bf_bits2f(ushort b) {
  return __uint_as_float(((uint)b) << 16);
}

__device__ __forceinline__ void split_vec4(const float* __restrict__ src,
                                           ushort* __restrict__ hi,
                                           ushort* __restrict__ lo, int idx) {
  const float4 v = ((const float4*)src)[idx];
  const float f[4] = {v.x, v.y, v.z, v.w};
  ushort4 h, l;
  ushort* hp = (ushort*)&h;
  ushort* lp = (ushort*)&l;
#pragma unroll
  for (int j = 0; j < 4; ++j) {
    const ushort hb = f2bf_bits(f[j]);
    hp[j] = hb;
    lp[j] = f2bf_bits(f[j] - bf_bits2f(hb));
  }
  ((ushort4*)hi)[idx] = h;
  ((ushort4*)lo)[idx] = l;
}

// ---------------------------------------------------------------------------
// Fused fp32 -> (hi,lo) bf16 split of three tensors (x, W_in, W_out).
// ---------------------------------------------------------------------------
__global__ __launch_bounds__(256) void split3_bf16_kernel(
    const float* __restrict__ s0, ushort* __restrict__ h0, ushort* __restrict__ l0, int n0v,
    const float* __restrict__ s1, ushort* __restrict__ h1, ushort* __restrict__ l1, int n1v,
    const float* __restrict__ s2, ushort* __restrict__ h2, ushort* __restrict__ l2) {
  int idx = blockIdx.x * 256 + threadIdx.x;
  if (idx < n0v) {
    split_vec4(s0, h0, l0, idx);
  } else if (idx < n0v + n1v) {
    split_vec4(s1, h1, l1, idx - n0v);
  } else {
    split_vec4(s2, h2, l2, idx - n0v - n1v);
  }
}

// ---------------------------------------------------------------------------
// MFMA GEMM on pre-split bf16 hi/lo operands, global_load_lds staging.
// C = Ahi·Bhi^T + Ahi·Blo^T + Alo·Bhi^T   (3-term Ootomo split)
// A* (M,K) ushort row-major, B* (N,K) ushort row-major, C (M,N) fp32.
// 256 threads = 4 waves in 2x2. BK=64. M%BM==0, N%BN==0, K%64==0.
// LDS tiles are LINEAR [BM][64] (gload_lds requires lane-order dest; the
// 16-lane same-column read conflict is off the critical path at 2-phase —
// m97/m230/m252).
// ---------------------------------------------------------------------------
template <int BM, int BN>
__global__ __launch_bounds__(256) void gemm_mfma_presplit(
    const ushort* __restrict__ Ah, const ushort* __restrict__ Al, int lda,
    const ushort* __restrict__ Bh, const ushort* __restrict__ Bl, int ldb,
    float* __restrict__ C, int ldc, int K) {
  __shared__ __align__(16) ushort As_hi[BM * 64];
  __shared__ __align__(16) ushort As_lo[BM * 64];
  __shared__ __align__(16) ushort Bs_hi[BN * 64];
  __shared__ __align__(16) ushort Bs_lo[BN * 64];

  const int tid = threadIdx.x;
  const int lane = tid & 63;
  const int wave = tid >> 6;
  const int wbase = tid & 192;  // wave*64, uniform within wave
  const int m0 = blockIdx.y * BM;
  const int n0 = blockIdx.x * BN;

  constexpr int FM = BM / 32;
  constexpr int FN = BN / 32;
  const int wm0 = (wave >> 1) * (BM / 2);
  const int wn0 = (wave & 1) * (BN / 2);
  const int fr = lane & 15;
  const int kg = lane >> 4;

  f32x4 acc[FM][FN] = {};

  for (int k0 = 0; k0 < K; k0 += 64) {
    // ---- stage via global_load_lds (no VGPR round-trip) ----
    // slot s covers LDS ushort range [s*8, s*8+8) == row (s>>3), col ((s&7)*8)
#pragma unroll
    for (int i = 0; i < BM / 32; ++i) {
      const int slot = i * 256 + tid;
      const int row = slot >> 3;
      const int c8 = (slot & 7) << 3;
      const size_t g = (size_t)(m0 + row) * lda + k0 + c8;
      const int lb = (i * 256 + wbase) * 8;  // wave-uniform LDS base slot
      gload16(&Ah[g], &As_hi[lb]);
      gload16(&Al[g], &As_lo[lb]);
    }
#pragma unroll
    for (int i = 0; i < BN / 32; ++i) {
      const int slot = i * 256 + tid;
      const int row = slot >> 3;
      const int c8 = (slot & 7) << 3;
      const size_t g = (size_t)(n0 + row) * ldb + k0 + c8;
      const int lb = (i * 256 + wbase) * 8;
      gload16(&Bh[g], &Bs_hi[lb]);
      gload16(&Bl[g], &Bs_lo[lb]);
    }
    __syncthreads();  // compiler drains vmcnt(0) before s_barrier

#pragma unroll
    for (int k2 = 0; k2 < 64; k2 += 32) {
      bf16x8 ah[FM], al[FM];
#pragma unroll
      for (int m = 0; m < FM; ++m) {
        const int base = (wm0 + m * 16 + fr) * 64 + k2 + kg * 8;
        ah[m] = *(const bf16x8*)&As_hi[base];
        al[m] = *(const bf16x8*)&As_lo[base];
      }
#pragma unroll
      for (int n = 0; n < FN; ++n) {
        const int base = (wn0 + n * 16 + fr) * 64 + k2 + kg * 8;
        const bf16x8 bh = *(const bf16x8*)&Bs_hi[base];
        const bf16x8 bl = *(const bf16x8*)&Bs_lo[base];
#pragma unroll
        for (int m = 0; m < FM; ++m) {
          acc[m][n] = __builtin_amdgcn_mfma_f32_16x16x32_bf16(ah[m], bh, acc[m][n], 0, 0, 0);
          acc[m][n] = __builtin_amdgcn_mfma_f32_16x16x32_bf16(ah[m], bl, acc[m][n], 0, 0, 0);
          acc[m][n] = __builtin_amdgcn_mfma_f32_16x16x32_bf16(al[m], bh, acc[m][n], 0, 0, 0);
        }
      }
    }
    __syncthreads();
  }

  // C/D layout: col = lane&15, row = (lane>>4)*4 + reg   [m89]
#pragma unroll
  for (int m = 0; m < FM; ++m) {
#pragma unroll
    for (int n = 0; n < FN; ++n) {
      const int row = m0 + wm0 + m * 16 + (lane >> 4) * 4;
      const int col = n0 + wn0 + n * 16 + (lane & 15);
#pragma unroll
      for (int r = 0; r < 4; ++r) C[(row + r) * ldc + col] = acc[m][n][r];
    }
  }
}

// ---------------------------------------------------------------------------
// GEMM2 split-K: part[ks] = xbc[:, ks*192:(ks+1)*192] @ W_x[:, same]^T
// Grid (SEQ/64, KS). Block 256 = 16x16; 4x5 micro-tile (N=80 = 16 cols x 5).
// ---------------------------------------------------------------------------
__global__ __launch_bounds__(256) void gemm2_splitk(
    const float* __restrict__ A,   // xbc (SEQ, D_INNER)
    const float* __restrict__ B,   // W_x (80, D_INNER)
    float* __restrict__ part) {    // (KS, SEQ, 80)
  __shared__ __align__(16) float As[16][68];
  __shared__ __align__(16) float Bs[16][84];

  const int tid = threadIdx.x;
  const int tx = tid & 15;
  const int ty = tid >> 4;
  const int m0 = blockIdx.x * 64;
  const int kbase = blockIdx.y * KCH;

  float acc[4][5] = {};

  for (int k0 = 0; k0 < KCH; k0 += 16) {
    {  // stage A 64x16
      const int am = tid >> 2;
      const int ak = (tid & 3) << 2;
      const float4 av = *(const float4*)&A[(m0 + am) * D_INNER + kbase + k0 + ak];
      As[ak + 0][am] = av.x;
      As[ak + 1][am] = av.y;
      As[ak + 2][am] = av.z;
      As[ak + 3][am] = av.w;
    }
    // stage B 80x16
    for (int f = tid; f < 80 * 4; f += 256) {
      const int row = f >> 2;
      const int kk = (f & 3) << 2;
      const float4 bv = *(const float4*)&B[row * D_INNER + kbase + k0 + kk];
      Bs[kk + 0][row] = bv.x;
      Bs[kk + 1][row] = bv.y;
      Bs[kk + 2][row] = bv.z;
      Bs[kk + 3][row] = bv.w;
    }
    __syncthreads();

#pragma unroll
    for (int k = 0; k < 16; ++k) {
      const float4 a4 = *(const float4*)&As[k][ty * 4];
      const float a[4] = {a4.x, a4.y, a4.z, a4.w};
      float b[5];
#pragma unroll
      for (int j = 0; j < 5; ++j) b[j] = Bs[k][tx + 16 * j];
#pragma unroll
      for (int i = 0; i < 4; ++i)
#pragma unroll
        for (int j = 0; j < 5; ++j) acc[i][j] = fmaf(a[i], b[j], acc[i][j]);
    }
    __syncthreads();
  }

  const int pb = (blockIdx.y * SEQ + m0) * 80;
#pragma unroll
  for (int i = 0; i < 4; ++i)
#pragma unroll
    for (int j = 0; j < 5; ++j)
      part[pb + (ty * 4 + i) * 80 + tx + 16 * j] = acc[i][j];
}

__global__ __launch_bounds__(256) void gemm2_reduce(
    const float* __restrict__ part, float* __restrict__ xdbl) {
  const int idx = blockIdx.x * 256 + threadIdx.x;  // < SEQ*80
  float s = 0.f;
#pragma unroll
  for (int ks = 0; ks < KS; ++ks) s += part[ks * SEQ * 80 + idx];
  xdbl[idx] = s;
}

// ---------------------------------------------------------------------------
// fp32 GEMM (GEMM3 only): C = softplus(A @ B^T + bias). 64x64 tile, BK=16.
// ---------------------------------------------------------------------------
template <int MODE>
__global__ __launch_bounds__(256) void gemm_kernel(
    const float* __restrict__ A, int lda,
    const float* __restrict__ B, int ldb,
    const float* __restrict__ bias,
    float* __restrict__ C, int ldc,
    int M, int N, int K) {
  __shared__ __align__(16) float As[16][68];
  __shared__ __align__(16) float Bs[16][68];

  const int tid = threadIdx.x;
  const int tx = tid & 15;
  const int ty = tid >> 4;
  const int m0 = blockIdx.y * 64;
  const int n0 = blockIdx.x * 64;

  const int am = tid >> 2;
  const int ak = (tid & 3) << 2;

  float acc[4][4] = {};

  for (int k0 = 0; k0 < K; k0 += 16) {
    {
      const float4 av = *(const float4*)&A[(m0 + am) * lda + k0 + ak];
      As[ak + 0][am] = av.x;
      As[ak + 1][am] = av.y;
      As[ak + 2][am] = av.z;
      As[ak + 3][am] = av.w;
    }
    {
      const int bn = n0 + am;
      float4 bv = make_float4(0.f, 0.f, 0.f, 0.f);
      if (bn < N) bv = *(const float4*)&B[bn * ldb + k0 + ak];
      Bs[ak + 0][am] = bv.x;
      Bs[ak + 1][am] = bv.y;
      Bs[ak + 2][am] = bv.z;
      Bs[ak + 3][am] = bv.w;
    }
    __syncthreads();

#pragma unroll
    for (int k = 0; k < 16; ++k) {
      const float4 a = *(const float4*)&As[k][ty * 4];
      const float4 b = *(const float4*)&Bs[k][tx * 4];
      const float ar[4] = {a.x, a.y, a.z, a.w};
      const float br[4] = {b.x, b.y, b.z, b.w};
#pragma unroll
      for (int i = 0; i < 4; ++i)
#pragma unroll
        for (int j = 0; j < 4; ++j) acc[i][j] = fmaf(ar[i], br[j], acc[i][j]);
    }
    __syncthreads();
  }

#pragma unroll
  for (int i = 0; i < 4; ++i) {
    const int m = m0 + ty * 4 + i;
#pragma unroll
    for (int j = 0; j < 4; ++j) {
      const int n = n0 + tx * 4 + j;
      if (n < N) {
        float v = acc[i][j];
        if (MODE == 1) {
          v += bias[n];
          v = (v > 20.f) ? v : log1pf(__expf(v));  // softplus
        }
        C[m * ldc + n] = v;
      }
    }
  }
}

// ---------------------------------------------------------------------------
// Depthwise causal conv (width 4) + bias + SiLU, vectorized x4 channels.
// ---------------------------------------------------------------------------
__global__ __launch_bounds__(256) void conv_silu_kernel(
    const float* __restrict__ xz, const float* __restrict__ cw,
    const float* __restrict__ cb, float* __restrict__ xbc) {
  const int idx = blockIdx.x * 256 + threadIdx.x;  // < SEQ * D_INNER/4
  const int t = idx / (D_INNER / 4);
  const int d = (idx - t * (D_INNER / 4)) * 4;
  const float4 w0 = *(const float4*)&cw[(d + 0) * 4];
  const float4 w1 = *(const float4*)&cw[(d + 1) * 4];
  const float4 w2 = *(const float4*)&cw[(d + 2) * 4];
  const float4 w3 = *(const float4*)&cw[(d + 3) * 4];
  float4 acc = *(const float4*)&cb[d];
#pragma unroll
  for (int j = 0; j < 4; ++j) {
    const int tt = t + j - 3;
    if (tt >= 0) {
      const float4 xv = *(const float4*)&xz[tt * (2 * D_INNER) + d];
      acc.x = fmaf(xv.x, ((const float*)&w0)[j], acc.x);
      acc.y = fmaf(xv.y, ((const float*)&w1)[j], acc.y);
      acc.z = fmaf(xv.z, ((const float*)&w2)[j], acc.z);
      acc.w = fmaf(xv.w, ((const float*)&w3)[j], acc.w);
    }
  }
  float4 r;
  r.x = acc.x / (1.f + __expf(-acc.x));
  r.y = acc.y / (1.f + __expf(-acc.y));
  r.z = acc.z / (1.f + __expf(-acc.z));
  r.w = acc.w / (1.f + __expf(-acc.w));
  *(float4*)&xbc[t * D_INNER + d] = r;
}

// ---------------------------------------------------------------------------
// Chunked selective scan, phase 1: per (chunk, d-group) local scan from h=0.
// ---------------------------------------------------------------------------
__global__ __launch_bounds__(256) void scan_part1(
    const float* __restrict__ dt, const float* __restrict__ xdbl,
    const float* __restrict__ xbc, const float* __restrict__ A_log,
    float* __restrict__ aprod, float* __restrict__ hloc) {
  __shared__ float dt_s[LC][16];
  __shared__ float xb_s[LC][16];
  __shared__ float B_s[LC][16];

  const int tid = threadIdx.x;
  const int ch = tid >> 4;
  const int n = tid & 15;
  const int d0 = blockIdx.x * 16;
  const int c = blockIdx.y;
  const int t0 = c * LC;

  for (int f = tid; f < LC * 16; f += 256) {
    const int t = f >> 4, cc = f & 15;
    const int gt = t0 + t;
    dt_s[t][cc] = dt[gt * D_INNER + d0 + cc];
    xb_s[t][cc] = xbc[gt * D_INNER + d0 + cc];
    B_s[t][cc] = xdbl[gt * 80 + DT_RANK + cc];
  }
  __syncthreads();

  const float Aval = -__expf(A_log[(d0 + ch) * D_STATE + n]);
  float h = 0.f, ap = 1.f;
#pragma unroll 4
  for (int t = 0; t < LC; ++t) {
    const float sdt = dt_s[t][ch];
    const float dA = __expf(sdt * Aval);
    h = fmaf(dA, h, sdt * B_s[t][n] * xb_s[t][ch]);
    ap *= dA;
  }
  const int idx = c * DN + d0 * 16 + tid;
  aprod[idx] = ap;
  hloc[idx] = h;
}

// ---------------------------------------------------------------------------
// Phase 2: sequential combine over the NC chunk summaries per (d,n).
// ---------------------------------------------------------------------------
__global__ __launch_bounds__(256) void scan_combine(
    const float* __restrict__ aprod, const float* __restrict__ hloc,
    float* __restrict__ hstart) {
  const int idx = blockIdx.x * 256 + threadIdx.x;  // < DN
  float hs = 0.f;
#pragma unroll
  for (int c = 0; c < NC; ++c) {
    const float a = aprod[c * DN + idx];
    const float hl = hloc[c * DN + idx];
    hstart[c * DN + idx] = hs;
    hs = fmaf(a, hs, hl);
  }
}

// ---------------------------------------------------------------------------
// Phase 3: re-scan each chunk from its true h_start; fused +xbc*D, *silu(z)
// epilogue; writes ym directly as pre-split bf16 hi/lo for GEMM4.
// ---------------------------------------------------------------------------
__global__ __launch_bounds__(256) void scan_part3(
    const float* __restrict__ dt, const float* __restrict__ xdbl,
    const float* __restrict__ xbc, const float* __restrict__ xz,
    const float* __restrict__ A_log, const float* __restrict__ Dp,
    const float* __restrict__ hstart,
    ushort* __restrict__ ym_hi, ushort* __restrict__ ym_lo) {
  __shared__ float dt_s[LC][16];
  __shared__ float xb_s[LC][16];
  __shared__ float z_s[LC][16];
  __shared__ float B_s[LC][16];
  __shared__ float C_s[LC][16];
  __shared__ float y_s[LC][16];

  const int tid = threadIdx.x;
  const int ch = tid >> 4;
  const int n = tid & 15;
  const int d0 = blockIdx.x * 16;
  const int c = blockIdx.y;
  const int t0 = c * LC;

  for (int f = tid; f < LC * 16; f += 256) {
    const int t = f >> 4, cc = f & 15;
    const int gt = t0 + t;
    dt_s[t][cc] = dt[gt * D_INNER + d0 + cc];
    xb_s[t][cc] = xbc[gt * D_INNER + d0 + cc];
    z_s[t][cc] = xz[gt * (2 * D_INNER) + D_INNER + d0 + cc];
    B_s[t][cc] = xdbl[gt * 80 + DT_RANK + cc];
    C_s[t][cc] = xdbl[gt * 80 + DT_RANK + D_STATE + cc];
  }
  __syncthreads();

  const float Aval = -__expf(A_log[(d0 + ch) * D_STATE + n]);
  const float Dval = Dp[d0 + ch];
  float h = hstart[c * DN + d0 * 16 + tid];

#pragma unroll 4
  for (int t = 0; t < LC; ++t) {
    const float sdt = dt_s[t][ch];
    const float bx = xb_s[t][ch];
    const float dA = __expf(sdt * Aval);
    h = fmaf(dA, h, sdt * B_s[t][n] * bx);
    float p = h * C_s[t][n];
    p += __shfl_xor(p, 1, 16);
    p += __shfl_xor(p, 2, 16);
    p += __shfl_xor(p, 4, 16);
    p += __shfl_xor(p, 8, 16);
    if (n == 0) {
      const float zz = z_s[t][ch];
      const float sig = 1.f / (1.f + __expf(-zz));
      y_s[t][ch] = (p + bx * Dval) * (zz * sig);
    }
  }
  __syncthreads();

  for (int f = tid; f < LC * 16; f += 256) {
    const int t = f >> 4, cc = f & 15;
    const float v = y_s[t][cc];
    const ushort hb = f2bf_bits(v);
    const int gidx = (t0 + t) * D_INNER + d0 + cc;
    ym_hi[gidx] = hb;
    ym_lo[gidx] = f2bf_bits(v - bf_bits2f(hb));
  }
}

// ---------------------------------------------------------------------------
extern "C" void kernel_launch(void* const* d_in, const int* in_sizes, int n_in,
                              void* d_out, int out_size, void* d_ws,
                              size_t ws_size, hipStream_t stream) {
  const float* x = (const float*)d_in[0];       // (2048, 768)
  const float* W_in = (const float*)d_in[1];    // (3072, 768)
  const float* conv_w = (const float*)d_in[2];  // (1536, 1, 4)
  const float* conv_b = (const float*)d_in[3];  // (1536,)
  const float* W_x = (const float*)d_in[4];     // (80, 1536)
  const float* W_dt = (const float*)d_in[5];    // (1536, 48)
  const float* b_dt = (const float*)d_in[6];    // (1536,)
  const float* A_log = (const float*)d_in[7];   // (1536, 16)
  const float* D_param = (const float*)d_in[8]; // (1536,)
  const float* W_out = (const float*)d_in[9];   // (768, 1536)
  float* out = (float*)d_out;                   // (2048, 768)

  // ---- workspace layout (fp32 region, then bf16 hi/lo region) ----
  float* ws = (float*)d_ws;
  float* xz = ws;                            // 2048*3072
  float* xbc = xz + SEQ * 2 * D_INNER;       // 2048*1536
  float* xdbl = xbc + SEQ * D_INNER;         // 2048*80
  float* dtb = xdbl + SEQ * 80;              // 2048*1536
  float* aprod = dtb + SEQ * D_INNER;        // NC*DN
  float* hloc = aprod + NC * DN;             // NC*DN
  float* hstart = hloc + NC * DN;            // NC*DN

  ushort* x_hi = (ushort*)(hstart + NC * DN);       // 2048*768
  ushort* x_lo = x_hi + SEQ * D_MODEL;
  ushort* wi_hi = x_lo + SEQ * D_MODEL;             // 3072*768
  ushort* wi_lo = wi_hi + 2 * D_INNER * D_MODEL;
  ushort* wo_hi = wi_lo + 2 * D_INNER * D_MODEL;    // 768*1536
  ushort* wo_lo = wo_hi + D_MODEL * D_INNER;
  ushort* ym_hi = wo_lo + D_MODEL * D_INNER;        // 2048*1536
  ushort* ym_lo = ym_hi + SEQ * D_INNER;

  // GEMM2 split-K partials (KS*SEQ*80 fp32 = 5.24 MB) alias the x_hi/x_lo
  // region (6.29 MB): dead once GEMM1 has completed, and gemm2_splitk runs
  // strictly after it.
  float* part = (float*)x_hi;

  const dim3 blk(256);

  // ---- pre-split x, W_in, W_out into bf16 hi/lo (single fused launch) ----
  const int n0v = SEQ * D_MODEL / 4;            // 393216
  const int n1v = 2 * D_INNER * D_MODEL / 4;    // 589824
  const int n2v = D_MODEL * D_INNER / 4;        // 294912
  split3_bf16_kernel<<<dim3((n0v + n1v + n2v) / 256), blk, 0, stream>>>(
      x, x_hi, x_lo, n0v, W_in, wi_hi, wi_lo, n1v, W_out, wo_hi, wo_lo);

  // xz = x @ W_in^T   (2048 x 3072), MFMA pre-split + gload_lds
  gemm_mfma_presplit<128, 128><<<dim3(2 * D_INNER / 128, SEQ / 128), blk, 0, stream>>>(
      x_hi, x_lo, D_MODEL, wi_hi, wi_lo, D_MODEL, xz, 2 * D_INNER, D_MODEL);

  // xbc = silu(causal_conv(xb) + conv_b), x4 vectorized
  conv_silu_kernel<<<dim3(SEQ * D_INNER / 1024), blk, 0, stream>>>(
      xz, conv_w, conv_b, xbc);

  // xdbl = xbc @ W_x^T   (2048 x 80), 8-way split-K + reduce
  gemm2_splitk<<<dim3(SEQ / 64, KS), blk, 0, stream>>>(xbc, W_x, part);
  gemm2_reduce<<<dim3(SEQ * 80 / 256), blk, 0, stream>>>(part, xdbl);

  // dtb = softplus(xdbl[:, :48] @ W_dt^T + b_dt)   (2048 x 1536), fp32
  gemm_kernel<1><<<dim3(D_INNER / 64, SEQ / 64), blk, 0, stream>>>(
      xdbl, 80, W_dt, DT_RANK, b_dt, dtb, D_INNER, SEQ, D_INNER, DT_RANK);

  // chunked scan: local scans -> combine -> finalize (writes ym as hi/lo)
  scan_part1<<<dim3(D_INNER / 16, NC), blk, 0, stream>>>(
      dtb, xdbl, xbc, A_log, aprod, hloc);
  scan_combine<<<dim3(DN / 256), blk, 0, stream>>>(aprod, hloc, hstart);
  scan_part3<<<dim3(D_INNER / 16, NC), blk, 0, stream>>>(
      dtb, xdbl, xbc, xz, A_log, D_param, hstart, ym_hi, ym_lo);

  // out = ym @ W_out^T   (2048 x 768), MFMA pre-split + gload_lds
  gemm_mfma_presplit<64, 64><<<dim3(D_MODEL / 64, SEQ / 64), blk, 0, stream>>>(
      ym_hi, ym_lo, D_INNER, wo_hi, wo_lo, D_INNER, out, D_MODEL, D_INNER);
}

// Round 10
// 267.743 us; speedup vs baseline: 3.4786x; 1.1401x over previous
//
#include <hip/hip_runtime.h>
#include <hip/hip_bf16.h>

#define D_MODEL 768
#define D_INNER 1536
#define D_STATE 16
#define DT_RANK 48
#define SEQ 2048
#define NC 32            // scan chunks
#define LC (SEQ / NC)    // 64 timesteps per chunk
#define DN (D_INNER * D_STATE)  // 24576 (d,n) pairs
#define KS 8             // GEMM2 split-K ways
#define KCH (D_INNER / KS)  // 192

typedef float f32x4 __attribute__((ext_vector_type(4)));
typedef short bf16x8 __attribute__((ext_vector_type(8)));

typedef const __attribute__((address_space(1))) unsigned int* gas_u32;
typedef __attribute__((address_space(3))) unsigned int* las_u32;

// async global->LDS, 16B per lane; LDS dest = uniform base + lane*16 (m104)
__device__ __forceinline__ void gload16(const void* g, void* l) {
  __builtin_amdgcn_global_load_lds((gas_u32)g, (las_u32)l, 16, 0, 0);
}

// Butterfly all-reduce (sum) over each 16-lane group, pure DPP (no LDS ops).
__device__ __forceinline__ float dpp_radd16(float v) {
  int x;
  x = __builtin_amdgcn_update_dpp(0, __float_as_int(v), 0xB1, 0xF, 0xF, true);  // quad_perm xor1
  v += __int_as_float(x);
  x = __builtin_amdgcn_update_dpp(0, __float_as_int(v), 0x4E, 0xF, 0xF, true);  // quad_perm xor2
  v += __int_as_float(x);
  x = __builtin_amdgcn_update_dpp(0, __float_as_int(v), 0x141, 0xF, 0xF, true); // row_half_mirror
  v += __int_as_float(x);
  x = __builtin_amdgcn_update_dpp(0, __float_as_int(v), 0x140, 0xF, 0xF, true); // row_mirror
  v += __int_as_float(x);
  return v;
}

// round-to-nearest-even fp32 -> bf16 bits
__device__ __forceinline__ ushort f2bf_bits(float f) {
  uint u = __float_as_uint(f);
  u += 0x7FFFu + ((u >> 16) & 1u);
  return (ushort)(u >> 16);
}
__device__ __forceinline__ float bf_bits2f(ushort b) {
  return __uint_as_float(((uint)b) << 16);
}

__device__ __forceinline__ void split_vec4(const float* __restrict__ src,
                                           ushort* __restrict__ hi,
                                           ushort* __restrict__ lo, int idx) {
  const float4 v = ((const float4*)src)[idx];
  const float f[4] = {v.x, v.y, v.z, v.w};
  ushort4 h, l;
  ushort* hp = (ushort*)&h;
  ushort* lp = (ushort*)&l;
#pragma unroll
  for (int j = 0; j < 4; ++j) {
    const ushort hb = f2bf_bits(f[j]);
    hp[j] = hb;
    lp[j] = f2bf_bits(f[j] - bf_bits2f(hb));
  }
  ((ushort4*)hi)[idx] = h;
  ((ushort4*)lo)[idx] = l;
}

// ---------------------------------------------------------------------------
// Fused fp32 -> (hi,lo) bf16 split of three tensors (x, W_in, W_out).
// ---------------------------------------------------------------------------
__global__ __launch_bounds__(256) void split3_bf16_kernel(
    const float* __restrict__ s0, ushort* __restrict__ h0, ushort* __restrict__ l0, int n0v,
    const float* __restrict__ s1, ushort* __restrict__ h1, ushort* __restrict__ l1, int n1v,
    const float* __restrict__ s2, ushort* __restrict__ h2, ushort* __restrict__ l2) {
  int idx = blockIdx.x * 256 + threadIdx.x;
  if (idx < n0v) {
    split_vec4(s0, h0, l0, idx);
  } else if (idx < n0v + n1v) {
    split_vec4(s1, h1, l1, idx - n0v);
  } else {
    split_vec4(s2, h2, l2, idx - n0v - n1v);
  }
}

// ---------------------------------------------------------------------------
// MFMA GEMM on pre-split bf16 hi/lo operands, global_load_lds staging.
// C = Ahi·Bhi^T + Ahi·Blo^T + Alo·Bhi^T   (3-term Ootomo split)
// ---------------------------------------------------------------------------
template <int BM, int BN>
__global__ __launch_bounds__(256) void gemm_mfma_presplit(
    const ushort* __restrict__ Ah, const ushort* __restrict__ Al, int lda,
    const ushort* __restrict__ Bh, const ushort* __restrict__ Bl, int ldb,
    float* __restrict__ C, int ldc, int K) {
  __shared__ __align__(16) ushort As_hi[BM * 64];
  __shared__ __align__(16) ushort As_lo[BM * 64];
  __shared__ __align__(16) ushort Bs_hi[BN * 64];
  __shared__ __align__(16) ushort Bs_lo[BN * 64];

  const int tid = threadIdx.x;
  const int lane = tid & 63;
  const int wave = tid >> 6;
  const int wbase = tid & 192;  // wave*64, uniform within wave
  const int m0 = blockIdx.y * BM;
  const int n0 = blockIdx.x * BN;

  constexpr int FM = BM / 32;
  constexpr int FN = BN / 32;
  const int wm0 = (wave >> 1) * (BM / 2);
  const int wn0 = (wave & 1) * (BN / 2);
  const int fr = lane & 15;
  const int kg = lane >> 4;

  f32x4 acc[FM][FN] = {};

  for (int k0 = 0; k0 < K; k0 += 64) {
#pragma unroll
    for (int i = 0; i < BM / 32; ++i) {
      const int slot = i * 256 + tid;
      const int row = slot >> 3;
      const int c8 = (slot & 7) << 3;
      const size_t g = (size_t)(m0 + row) * lda + k0 + c8;
      const int lb = (i * 256 + wbase) * 8;  // wave-uniform LDS base slot
      gload16(&Ah[g], &As_hi[lb]);
      gload16(&Al[g], &As_lo[lb]);
    }
#pragma unroll
    for (int i = 0; i < BN / 32; ++i) {
      const int slot = i * 256 + tid;
      const int row = slot >> 3;
      const int c8 = (slot & 7) << 3;
      const size_t g = (size_t)(n0 + row) * ldb + k0 + c8;
      const int lb = (i * 256 + wbase) * 8;
      gload16(&Bh[g], &Bs_hi[lb]);
      gload16(&Bl[g], &Bs_lo[lb]);
    }
    __syncthreads();

#pragma unroll
    for (int k2 = 0; k2 < 64; k2 += 32) {
      bf16x8 ah[FM], al[FM];
#pragma unroll
      for (int m = 0; m < FM; ++m) {
        const int base = (wm0 + m * 16 + fr) * 64 + k2 + kg * 8;
        ah[m] = *(const bf16x8*)&As_hi[base];
        al[m] = *(const bf16x8*)&As_lo[base];
      }
#pragma unroll
      for (int n = 0; n < FN; ++n) {
        const int base = (wn0 + n * 16 + fr) * 64 + k2 + kg * 8;
        const bf16x8 bh = *(const bf16x8*)&Bs_hi[base];
        const bf16x8 bl = *(const bf16x8*)&Bs_lo[base];
#pragma unroll
        for (int m = 0; m < FM; ++m) {
          acc[m][n] = __builtin_amdgcn_mfma_f32_16x16x32_bf16(ah[m], bh, acc[m][n], 0, 0, 0);
          acc[m][n] = __builtin_amdgcn_mfma_f32_16x16x32_bf16(ah[m], bl, acc[m][n], 0, 0, 0);
          acc[m][n] = __builtin_amdgcn_mfma_f32_16x16x32_bf16(al[m], bh, acc[m][n], 0, 0, 0);
        }
      }
    }
    __syncthreads();
  }

  // C/D layout: col = lane&15, row = (lane>>4)*4 + reg   [m89]
#pragma unroll
  for (int m = 0; m < FM; ++m) {
#pragma unroll
    for (int n = 0; n < FN; ++n) {
      const int row = m0 + wm0 + m * 16 + (lane >> 4) * 4;
      const int col = n0 + wn0 + n * 16 + (lane & 15);
#pragma unroll
      for (int r = 0; r < 4; ++r) C[(row + r) * ldc + col] = acc[m][n][r];
    }
  }
}

// ---------------------------------------------------------------------------
// GEMM2 split-K: part[ks] = xbc[:, ks*192:(ks+1)*192] @ W_x[:, same]^T
// ---------------------------------------------------------------------------
__global__ __launch_bounds__(256) void gemm2_splitk(
    const float* __restrict__ A,   // xbc (SEQ, D_INNER)
    const float* __restrict__ B,   // W_x (80, D_INNER)
    float* __restrict__ part) {    // (KS, SEQ, 80)
  __shared__ __align__(16) float As[16][68];
  __shared__ __align__(16) float Bs[16][84];

  const int tid = threadIdx.x;
  const int tx = tid & 15;
  const int ty = tid >> 4;
  const int m0 = blockIdx.x * 64;
  const int kbase = blockIdx.y * KCH;

  float acc[4][5] = {};

  for (int k0 = 0; k0 < KCH; k0 += 16) {
    {  // stage A 64x16
      const int am = tid >> 2;
      const int ak = (tid & 3) << 2;
      const float4 av = *(const float4*)&A[(m0 + am) * D_INNER + kbase + k0 + ak];
      As[ak + 0][am] = av.x;
      As[ak + 1][am] = av.y;
      As[ak + 2][am] = av.z;
      As[ak + 3][am] = av.w;
    }
    // stage B 80x16
    for (int f = tid; f < 80 * 4; f += 256) {
      const int row = f >> 2;
      const int kk = (f & 3) << 2;
      const float4 bv = *(const float4*)&B[row * D_INNER + kbase + k0 + kk];
      Bs[kk + 0][row] = bv.x;
      Bs[kk + 1][row] = bv.y;
      Bs[kk + 2][row] = bv.z;
      Bs[kk + 3][row] = bv.w;
    }
    __syncthreads();

#pragma unroll
    for (int k = 0; k < 16; ++k) {
      const float4 a4 = *(const float4*)&As[k][ty * 4];
      const float a[4] = {a4.x, a4.y, a4.z, a4.w};
      float b[5];
#pragma unroll
      for (int j = 0; j < 5; ++j) b[j] = Bs[k][tx + 16 * j];
#pragma unroll
      for (int i = 0; i < 4; ++i)
#pragma unroll
        for (int j = 0; j < 5; ++j) acc[i][j] = fmaf(a[i], b[j], acc[i][j]);
    }
    __syncthreads();
  }

  const int pb = (blockIdx.y * SEQ + m0) * 80;
#pragma unroll
  for (int i = 0; i < 4; ++i)
#pragma unroll
    for (int j = 0; j < 5; ++j)
      part[pb + (ty * 4 + i) * 80 + tx + 16 * j] = acc[i][j];
}

__global__ __launch_bounds__(256) void gemm2_reduce(
    const float* __restrict__ part, float* __restrict__ xdbl) {
  const int idx = blockIdx.x * 256 + threadIdx.x;  // < SEQ*80
  float s = 0.f;
#pragma unroll
  for (int ks = 0; ks < KS; ++ks) s += part[ks * SEQ * 80 + idx];
  xdbl[idx] = s;
}

// ---------------------------------------------------------------------------
// fp32 GEMM (GEMM3 only): C = softplus(A @ B^T + bias). 64x64 tile, BK=16.
// ---------------------------------------------------------------------------
template <int MODE>
__global__ __launch_bounds__(256) void gemm_kernel(
    const float* __restrict__ A, int lda,
    const float* __restrict__ B, int ldb,
    const float* __restrict__ bias,
    float* __restrict__ C, int ldc,
    int M, int N, int K) {
  __shared__ __align__(16) float As[16][68];
  __shared__ __align__(16) float Bs[16][68];

  const int tid = threadIdx.x;
  const int tx = tid & 15;
  const int ty = tid >> 4;
  const int m0 = blockIdx.y * 64;
  const int n0 = blockIdx.x * 64;

  const int am = tid >> 2;
  const int ak = (tid & 3) << 2;

  float acc[4][4] = {};

  for (int k0 = 0; k0 < K; k0 += 16) {
    {
      const float4 av = *(const float4*)&A[(m0 + am) * lda + k0 + ak];
      As[ak + 0][am] = av.x;
      As[ak + 1][am] = av.y;
      As[ak + 2][am] = av.z;
      As[ak + 3][am] = av.w;
    }
    {
      const int bn = n0 + am;
      float4 bv = make_float4(0.f, 0.f, 0.f, 0.f);
      if (bn < N) bv = *(const float4*)&B[bn * ldb + k0 + ak];
      Bs[ak + 0][am] = bv.x;
      Bs[ak + 1][am] = bv.y;
      Bs[ak + 2][am] = bv.z;
      Bs[ak + 3][am] = bv.w;
    }
    __syncthreads();

#pragma unroll
    for (int k = 0; k < 16; ++k) {
      const float4 a = *(const float4*)&As[k][ty * 4];
      const float4 b = *(const float4*)&Bs[k][tx * 4];
      const float ar[4] = {a.x, a.y, a.z, a.w};
      const float br[4] = {b.x, b.y, b.z, b.w};
#pragma unroll
      for (int i = 0; i < 4; ++i)
#pragma unroll
        for (int j = 0; j < 4; ++j) acc[i][j] = fmaf(ar[i], br[j], acc[i][j]);
    }
    __syncthreads();
  }

#pragma unroll
  for (int i = 0; i < 4; ++i) {
    const int m = m0 + ty * 4 + i;
#pragma unroll
    for (int j = 0; j < 4; ++j) {
      const int n = n0 + tx * 4 + j;
      if (n < N) {
        float v = acc[i][j];
        if (MODE == 1) {
          v += bias[n];
          v = (v > 20.f) ? v : log1pf(__expf(v));  // softplus
        }
        C[m * ldc + n] = v;
      }
    }
  }
}

// ---------------------------------------------------------------------------
// Depthwise causal conv (width 4) + bias + SiLU, vectorized x4 channels.
// ---------------------------------------------------------------------------
__global__ __launch_bounds__(256) void conv_silu_kernel(
    const float* __restrict__ xz, const float* __restrict__ cw,
    const float* __restrict__ cb, float* __restrict__ xbc) {
  const int idx = blockIdx.x * 256 + threadIdx.x;  // < SEQ * D_INNER/4
  const int t = idx / (D_INNER / 4);
  const int d = (idx - t * (D_INNER / 4)) * 4;
  const float4 w0 = *(const float4*)&cw[(d + 0) * 4];
  const float4 w1 = *(const float4*)&cw[(d + 1) * 4];
  const float4 w2 = *(const float4*)&cw[(d + 2) * 4];
  const float4 w3 = *(const float4*)&cw[(d + 3) * 4];
  float4 acc = *(const float4*)&cb[d];
#pragma unroll
  for (int j = 0; j < 4; ++j) {
    const int tt = t + j - 3;
    if (tt >= 0) {
      const float4 xv = *(const float4*)&xz[tt * (2 * D_INNER) + d];
      acc.x = fmaf(xv.x, ((const float*)&w0)[j], acc.x);
      acc.y = fmaf(xv.y, ((const float*)&w1)[j], acc.y);
      acc.z = fmaf(xv.z, ((const float*)&w2)[j], acc.z);
      acc.w = fmaf(xv.w, ((const float*)&w3)[j], acc.w);
    }
  }
  float4 r;
  r.x = acc.x / (1.f + __expf(-acc.x));
  r.y = acc.y / (1.f + __expf(-acc.y));
  r.z = acc.z / (1.f + __expf(-acc.z));
  r.w = acc.w / (1.f + __expf(-acc.w));
  *(float4*)&xbc[t * D_INNER + d] = r;
}

// ---------------------------------------------------------------------------
// Chunked selective scan, phase 1: per (chunk, d-group) local scan from h=0.
// Transposed LDS [ch][t] -> b128 reads over 4 timesteps.
// ---------------------------------------------------------------------------
__global__ __launch_bounds__(256) void scan_part1(
    const float* __restrict__ dt, const float* __restrict__ xdbl,
    const float* __restrict__ xbc, const float* __restrict__ A_log,
    float* __restrict__ aprod, float* __restrict__ hloc) {
  __shared__ __align__(16) float dt_s[16][68];
  __shared__ __align__(16) float xb_s[16][68];
  __shared__ __align__(16) float B_s[16][68];

  const int tid = threadIdx.x;
  const int ch = tid >> 4;
  const int n = tid & 15;
  const int d0 = blockIdx.x * 16;
  const int c = blockIdx.y;
  const int t0 = c * LC;

  for (int f = tid; f < LC * 16; f += 256) {
    const int t = f >> 4, cc = f & 15;
    const int gt = t0 + t;
    dt_s[cc][t] = dt[gt * D_INNER + d0 + cc];
    xb_s[cc][t] = xbc[gt * D_INNER + d0 + cc];
    B_s[cc][t] = xdbl[gt * 80 + DT_RANK + cc];
  }
  __syncthreads();

  const float Aval = -__expf(A_log[(d0 + ch) * D_STATE + n]);
  float h = 0.f, ap = 1.f;
  for (int t4 = 0; t4 < LC; t4 += 4) {
    const float4 dtv = *(const float4*)&dt_s[ch][t4];
    const float4 xbv = *(const float4*)&xb_s[ch][t4];
    const float4 Bv = *(const float4*)&B_s[n][t4];
#pragma unroll
    for (int j = 0; j < 4; ++j) {
      const float sdt = ((const float*)&dtv)[j];
      const float dA = __expf(sdt * Aval);
      h = fmaf(dA, h, sdt * ((const float*)&Bv)[j] * ((const float*)&xbv)[j]);
      ap *= dA;
    }
  }
  const int idx = c * DN + d0 * 16 + tid;
  aprod[idx] = ap;
  hloc[idx] = h;
}

// ---------------------------------------------------------------------------
// Phase 2: sequential combine over the NC chunk summaries per (d,n).
// ---------------------------------------------------------------------------
__global__ __launch_bounds__(256) void scan_combine(
    const float* __restrict__ aprod, const float* __restrict__ hloc,
    float* __restrict__ hstart) {
  const int idx = blockIdx.x * 256 + threadIdx.x;  // < DN
  float hs = 0.f;
#pragma unroll
  for (int c = 0; c < NC; ++c) {
    const float a = aprod[c * DN + idx];
    const float hl = hloc[c * DN + idx];
    hstart[c * DN + idx] = hs;
    hs = fmaf(a, hs, hl);
  }
}

// ---------------------------------------------------------------------------
// Phase 3: re-scan each chunk from its true h_start. Transposed LDS [ch][t],
// DPP butterfly reduce (no DS ops in the t-loop), silu(z)/D epilogue moved
// to the vectorized writeout. Writes ym directly as bf16 hi/lo for GEMM4.
// ---------------------------------------------------------------------------
__global__ __launch_bounds__(256) void scan_part3(
    const float* __restrict__ dt, const float* __restrict__ xdbl,
    const float* __restrict__ xbc, const float* __restrict__ xz,
    const float* __restrict__ A_log, const float* __restrict__ Dp,
    const float* __restrict__ hstart,
    ushort* __restrict__ ym_hi, ushort* __restrict__ ym_lo) {
  __shared__ __align__(16) float dt_s[16][68];
  __shared__ __align__(16) float xb_s[16][68];
  __shared__ __align__(16) float B_s[16][68];
  __shared__ __align__(16) float C_s[16][68];
  __shared__ float y_s[LC][16];

  const int tid = threadIdx.x;
  const int ch = tid >> 4;
  const int n = tid & 15;
  const int d0 = blockIdx.x * 16;
  const int c = blockIdx.y;
  const int t0 = c * LC;

  for (int f = tid; f < LC * 16; f += 256) {
    const int t = f >> 4, cc = f & 15;
    const int gt = t0 + t;
    dt_s[cc][t] = dt[gt * D_INNER + d0 + cc];
    xb_s[cc][t] = xbc[gt * D_INNER + d0 + cc];
    B_s[cc][t] = xdbl[gt * 80 + DT_RANK + cc];
    C_s[cc][t] = xdbl[gt * 80 + DT_RANK + D_STATE + cc];
  }
  __syncthreads();

  const float Aval = -__expf(A_log[(d0 + ch) * D_STATE + n]);
  float h = hstart[c * DN + d0 * 16 + tid];

  for (int t4 = 0; t4 < LC; t4 += 4) {
    const float4 dtv = *(const float4*)&dt_s[ch][t4];
    const float4 xbv = *(const float4*)&xb_s[ch][t4];
    const float4 Bv = *(const float4*)&B_s[n][t4];
    const float4 Cv = *(const float4*)&C_s[n][t4];
#pragma unroll
    for (int j = 0; j < 4; ++j) {
      const float sdt = ((const float*)&dtv)[j];
      const float dA = __expf(sdt * Aval);
      h = fmaf(dA, h, sdt * ((const float*)&Bv)[j] * ((const float*)&xbv)[j]);
      const float p = dpp_radd16(h * ((const float*)&Cv)[j]);
      if (n == 0) y_s[t4 + j][ch] = p;
    }
  }
  __syncthreads();

  // writeout: apply +xb*D and *silu(z), split to bf16 hi/lo
  for (int f = tid; f < LC * 16; f += 256) {
    const int t = f >> 4, cc = f & 15;
    const int gt = t0 + t;
    const float zz = xz[gt * (2 * D_INNER) + D_INNER + d0 + cc];
    const float sig = 1.f / (1.f + __expf(-zz));
    const float v = (y_s[t][cc] + xb_s[cc][t] * Dp[d0 + cc]) * (zz * sig);
    const ushort hb = f2bf_bits(v);
    const int gidx = gt * D_INNER + d0 + cc;
    ym_hi[gidx] = hb;
    ym_lo[gidx] = f2bf_bits(v - bf_bits2f(hb));
  }
}

// ---------------------------------------------------------------------------
extern "C" void kernel_launch(void* const* d_in, const int* in_sizes, int n_in,
                              void* d_out, int out_size, void* d_ws,
                              size_t ws_size, hipStream_t stream) {
  const float* x = (const float*)d_in[0];       // (2048, 768)
  const float* W_in = (const float*)d_in[1];    // (3072, 768)
  const float* conv_w = (const float*)d_in[2];  // (1536, 1, 4)
  const float* conv_b = (const float*)d_in[3];  // (1536,)
  const float* W_x = (const float*)d_in[4];     // (80, 1536)
  const float* W_dt = (const float*)d_in[5];    // (1536, 48)
  const float* b_dt = (const float*)d_in[6];    // (1536,)
  const float* A_log = (const float*)d_in[7];   // (1536, 16)
  const float* D_param = (const float*)d_in[8]; // (1536,)
  const float* W_out = (const float*)d_in[9];   // (768, 1536)
  float* out = (float*)d_out;                   // (2048, 768)

  // ---- workspace layout (fp32 region, then bf16 hi/lo region) ----
  float* ws = (float*)d_ws;
  float* xz = ws;                            // 2048*3072
  float* xbc = xz + SEQ * 2 * D_INNER;       // 2048*1536
  float* xdbl = xbc + SEQ * D_INNER;         // 2048*80
  float* dtb = xdbl + SEQ * 80;              // 2048*1536
  float* aprod = dtb + SEQ * D_INNER;        // NC*DN
  float* hloc = aprod + NC * DN;             // NC*DN
  float* hstart = hloc + NC * DN;            // NC*DN

  ushort* x_hi = (ushort*)(hstart + NC * DN);       // 2048*768
  ushort* x_lo = x_hi + SEQ * D_MODEL;
  ushort* wi_hi = x_lo + SEQ * D_MODEL;             // 3072*768
  ushort* wi_lo = wi_hi + 2 * D_INNER * D_MODEL;
  ushort* wo_hi = wi_lo + 2 * D_INNER * D_MODEL;    // 768*1536
  ushort* wo_lo = wo_hi + D_MODEL * D_INNER;
  ushort* ym_hi = wo_lo + D_MODEL * D_INNER;        // 2048*1536
  ushort* ym_lo = ym_hi + SEQ * D_INNER;

  // GEMM2 split-K partials alias the x_hi/x_lo region (dead after GEMM1).
  float* part = (float*)x_hi;

  const dim3 blk(256);

  // ---- pre-split x, W_in, W_out into bf16 hi/lo (single fused launch) ----
  const int n0v = SEQ * D_MODEL / 4;            // 393216
  const int n1v = 2 * D_INNER * D_MODEL / 4;    // 589824
  const int n2v = D_MODEL * D_INNER / 4;        // 294912
  split3_bf16_kernel<<<dim3((n0v + n1v + n2v) / 256), blk, 0, stream>>>(
      x, x_hi, x_lo, n0v, W_in, wi_hi, wi_lo, n1v, W_out, wo_hi, wo_lo);

  // xz = x @ W_in^T   (2048 x 3072), MFMA pre-split + gload_lds
  gemm_mfma_presplit<128, 128><<<dim3(2 * D_INNER / 128, SEQ / 128), blk, 0, stream>>>(
      x_hi, x_lo, D_MODEL, wi_hi, wi_lo, D_MODEL, xz, 2 * D_INNER, D_MODEL);

  // xbc = silu(causal_conv(xb) + conv_b), x4 vectorized
  conv_silu_kernel<<<dim3(SEQ * D_INNER / 1024), blk, 0, stream>>>(
      xz, conv_w, conv_b, xbc);

  // xdbl = xbc @ W_x^T   (2048 x 80), 8-way split-K + reduce
  gemm2_splitk<<<dim3(SEQ / 64, KS), blk, 0, stream>>>(xbc, W_x, part);
  gemm2_reduce<<<dim3(SEQ * 80 / 256), blk, 0, stream>>>(part, xdbl);

  // dtb = softplus(xdbl[:, :48] @ W_dt^T + b_dt)   (2048 x 1536), fp32
  gemm_kernel<1><<<dim3(D_INNER / 64, SEQ / 64), blk, 0, stream>>>(
      xdbl, 80, W_dt, DT_RANK, b_dt, dtb, D_INNER, SEQ, D_INNER, DT_RANK);

  // chunked scan: local scans -> combine -> finalize (writes ym as hi/lo)
  scan_part1<<<dim3(D_INNER / 16, NC), blk, 0, stream>>>(
      dtb, xdbl, xbc, A_log, aprod, hloc);
  scan_combine<<<dim3(DN / 256), blk, 0, stream>>>(aprod, hloc, hstart);
  scan_part3<<<dim3(D_INNER / 16, NC), blk, 0, stream>>>(
      dtb, xdbl, xbc, xz, A_log, D_param, hstart, ym_hi, ym_lo);

  // out = ym @ W_out^T   (2048 x 768), MFMA pre-split + gload_lds
  gemm_mfma_presplit<64, 64><<<dim3(D_MODEL / 64, SEQ / 64), blk, 0, stream>>>(
      ym_hi, ym_lo, D_INNER, wo_hi, wo_lo, D_INNER, out, D_MODEL, D_INNER);
}

// Round 11
// 265.543 us; speedup vs baseline: 3.5074x; 1.0083x over previous
//
#include <hip/hip_runtime.h>
#include <hip/hip_bf16.h>

#define D_MODEL 768
#define D_INNER 1536
#define D_STATE 16
#define DT_RANK 48
#define SEQ 2048
#define NC 32            // scan chunks
#define LC (SEQ / NC)    // 64 timesteps per chunk
#define DN (D_INNER * D_STATE)  // 24576 (d,n) pairs
#define KS 8             // GEMM2 split-K ways
#define KCH (D_INNER / KS)  // 192

typedef float f32x4 __attribute__((ext_vector_type(4)));
typedef short bf16x8 __attribute__((ext_vector_type(8)));

typedef const __attribute__((address_space(1))) unsigned int* gas_u32;
typedef __attribute__((address_space(3))) unsigned int* las_u32;

// async global->LDS, 16B per lane; LDS dest = uniform base + lane*16 (m104)
__device__ __forceinline__ void gload16(const void* g, void* l) {
  __builtin_amdgcn_global_load_lds((gas_u32)g, (las_u32)l, 16, 0, 0);
}

// Butterfly all-reduce (sum) over each 16-lane group, pure DPP (no LDS ops).
__device__ __forceinline__ float dpp_radd16(float v) {
  int x;
  x = __builtin_amdgcn_update_dpp(0, __float_as_int(v), 0xB1, 0xF, 0xF, true);  // quad_perm xor1
  v += __int_as_float(x);
  x = __builtin_amdgcn_update_dpp(0, __float_as_int(v), 0x4E, 0xF, 0xF, true);  // quad_perm xor2
  v += __int_as_float(x);
  x = __builtin_amdgcn_update_dpp(0, __float_as_int(v), 0x141, 0xF, 0xF, true); // row_half_mirror
  v += __int_as_float(x);
  x = __builtin_amdgcn_update_dpp(0, __float_as_int(v), 0x140, 0xF, 0xF, true); // row_mirror
  v += __int_as_float(x);
  return v;
}

// round-to-nearest-even fp32 -> bf16 bits
__device__ __forceinline__ ushort f2bf_bits(float f) {
  uint u = __float_as_uint(f);
  u += 0x7FFFu + ((u >> 16) & 1u);
  return (ushort)(u >> 16);
}
__device__ __forceinline__ float bf_bits2f(ushort b) {
  return __uint_as_float(((uint)b) << 16);
}

__device__ __forceinline__ void split_vec4(const float* __restrict__ src,
                                           ushort* __restrict__ hi,
                                           ushort* __restrict__ lo, int idx) {
  const float4 v = ((const float4*)src)[idx];
  const float f[4] = {v.x, v.y, v.z, v.w};
  ushort4 h, l;
  ushort* hp = (ushort*)&h;
  ushort* lp = (ushort*)&l;
#pragma unroll
  for (int j = 0; j < 4; ++j) {
    const ushort hb = f2bf_bits(f[j]);
    hp[j] = hb;
    lp[j] = f2bf_bits(f[j] - bf_bits2f(hb));
  }
  ((ushort4*)hi)[idx] = h;
  ((ushort4*)lo)[idx] = l;
}

// ---------------------------------------------------------------------------
// Fused fp32 -> (hi,lo) bf16 split of three tensors (x, W_in, W_out).
// ---------------------------------------------------------------------------
__global__ __launch_bounds__(256) void split3_bf16_kernel(
    const float* __restrict__ s0, ushort* __restrict__ h0, ushort* __restrict__ l0, int n0v,
    const float* __restrict__ s1, ushort* __restrict__ h1, ushort* __restrict__ l1, int n1v,
    const float* __restrict__ s2, ushort* __restrict__ h2, ushort* __restrict__ l2) {
  int idx = blockIdx.x * 256 + threadIdx.x;
  if (idx < n0v) {
    split_vec4(s0, h0, l0, idx);
  } else if (idx < n0v + n1v) {
    split_vec4(s1, h1, l1, idx - n0v);
  } else {
    split_vec4(s2, h2, l2, idx - n0v - n1v);
  }
}

// ---------------------------------------------------------------------------
// MFMA GEMM on pre-split bf16 hi/lo operands, global_load_lds staging.
// C = Ahi·Bhi^T + Ahi·Blo^T + Alo·Bhi^T   (3-term Ootomo split)
// GEMM1 uses <128,64>: 768 blocks = 3.0 blocks/CU exact (no tail), LDS 48 KB
// -> 3 resident blocks/CU, 12 waves/CU of implicit overlap (m114 regime).
// ---------------------------------------------------------------------------
template <int BM, int BN>
__global__ __launch_bounds__(256) void gemm_mfma_presplit(
    const ushort* __restrict__ Ah, const ushort* __restrict__ Al, int lda,
    const ushort* __restrict__ Bh, const ushort* __restrict__ Bl, int ldb,
    float* __restrict__ C, int ldc, int K) {
  __shared__ __align__(16) ushort As_hi[BM * 64];
  __shared__ __align__(16) ushort As_lo[BM * 64];
  __shared__ __align__(16) ushort Bs_hi[BN * 64];
  __shared__ __align__(16) ushort Bs_lo[BN * 64];

  const int tid = threadIdx.x;
  const int lane = tid & 63;
  const int wave = tid >> 6;
  const int wbase = tid & 192;  // wave*64, uniform within wave
  const int m0 = blockIdx.y * BM;
  const int n0 = blockIdx.x * BN;

  constexpr int FM = BM / 32;
  constexpr int FN = BN / 32;
  const int wm0 = (wave >> 1) * (BM / 2);
  const int wn0 = (wave & 1) * (BN / 2);
  const int fr = lane & 15;
  const int kg = lane >> 4;

  f32x4 acc[FM][FN] = {};

  for (int k0 = 0; k0 < K; k0 += 64) {
#pragma unroll
    for (int i = 0; i < BM / 32; ++i) {
      const int slot = i * 256 + tid;
      const int row = slot >> 3;
      const int c8 = (slot & 7) << 3;
      const size_t g = (size_t)(m0 + row) * lda + k0 + c8;
      const int lb = (i * 256 + wbase) * 8;  // wave-uniform LDS base slot
      gload16(&Ah[g], &As_hi[lb]);
      gload16(&Al[g], &As_lo[lb]);
    }
#pragma unroll
    for (int i = 0; i < BN / 32; ++i) {
      const int slot = i * 256 + tid;
      const int row = slot >> 3;
      const int c8 = (slot & 7) << 3;
      const size_t g = (size_t)(n0 + row) * ldb + k0 + c8;
      const int lb = (i * 256 + wbase) * 8;
      gload16(&Bh[g], &Bs_hi[lb]);
      gload16(&Bl[g], &Bs_lo[lb]);
    }
    __syncthreads();

#pragma unroll
    for (int k2 = 0; k2 < 64; k2 += 32) {
      bf16x8 ah[FM], al[FM];
#pragma unroll
      for (int m = 0; m < FM; ++m) {
        const int base = (wm0 + m * 16 + fr) * 64 + k2 + kg * 8;
        ah[m] = *(const bf16x8*)&As_hi[base];
        al[m] = *(const bf16x8*)&As_lo[base];
      }
#pragma unroll
      for (int n = 0; n < FN; ++n) {
        const int base = (wn0 + n * 16 + fr) * 64 + k2 + kg * 8;
        const bf16x8 bh = *(const bf16x8*)&Bs_hi[base];
        const bf16x8 bl = *(const bf16x8*)&Bs_lo[base];
#pragma unroll
        for (int m = 0; m < FM; ++m) {
          acc[m][n] = __builtin_amdgcn_mfma_f32_16x16x32_bf16(ah[m], bh, acc[m][n], 0, 0, 0);
          acc[m][n] = __builtin_amdgcn_mfma_f32_16x16x32_bf16(ah[m], bl, acc[m][n], 0, 0, 0);
          acc[m][n] = __builtin_amdgcn_mfma_f32_16x16x32_bf16(al[m], bh, acc[m][n], 0, 0, 0);
        }
      }
    }
    __syncthreads();
  }

  // C/D layout: col = lane&15, row = (lane>>4)*4 + reg   [m89]
#pragma unroll
  for (int m = 0; m < FM; ++m) {
#pragma unroll
    for (int n = 0; n < FN; ++n) {
      const int row = m0 + wm0 + m * 16 + (lane >> 4) * 4;
      const int col = n0 + wn0 + n * 16 + (lane & 15);
#pragma unroll
      for (int r = 0; r < 4; ++r) C[(row + r) * ldc + col] = acc[m][n][r];
    }
  }
}

// ---------------------------------------------------------------------------
// GEMM2 split-K: part[ks] = xbc[:, ks*192:(ks+1)*192] @ W_x[:, same]^T
// ---------------------------------------------------------------------------
__global__ __launch_bounds__(256) void gemm2_splitk(
    const float* __restrict__ A,   // xbc (SEQ, D_INNER)
    const float* __restrict__ B,   // W_x (80, D_INNER)
    float* __restrict__ part) {    // (KS, SEQ, 80)
  __shared__ __align__(16) float As[16][68];
  __shared__ __align__(16) float Bs[16][84];

  const int tid = threadIdx.x;
  const int tx = tid & 15;
  const int ty = tid >> 4;
  const int m0 = blockIdx.x * 64;
  const int kbase = blockIdx.y * KCH;

  float acc[4][5] = {};

  for (int k0 = 0; k0 < KCH; k0 += 16) {
    {  // stage A 64x16
      const int am = tid >> 2;
      const int ak = (tid & 3) << 2;
      const float4 av = *(const float4*)&A[(m0 + am) * D_INNER + kbase + k0 + ak];
      As[ak + 0][am] = av.x;
      As[ak + 1][am] = av.y;
      As[ak + 2][am] = av.z;
      As[ak + 3][am] = av.w;
    }
    // stage B 80x16
    for (int f = tid; f < 80 * 4; f += 256) {
      const int row = f >> 2;
      const int kk = (f & 3) << 2;
      const float4 bv = *(const float4*)&B[row * D_INNER + kbase + k0 + kk];
      Bs[kk + 0][row] = bv.x;
      Bs[kk + 1][row] = bv.y;
      Bs[kk + 2][row] = bv.z;
      Bs[kk + 3][row] = bv.w;
    }
    __syncthreads();

#pragma unroll
    for (int k = 0; k < 16; ++k) {
      const float4 a4 = *(const float4*)&As[k][ty * 4];
      const float a[4] = {a4.x, a4.y, a4.z, a4.w};
      float b[5];
#pragma unroll
      for (int j = 0; j < 5; ++j) b[j] = Bs[k][tx + 16 * j];
#pragma unroll
      for (int i = 0; i < 4; ++i)
#pragma unroll
        for (int j = 0; j < 5; ++j) acc[i][j] = fmaf(a[i], b[j], acc[i][j]);
    }
    __syncthreads();
  }

  const int pb = (blockIdx.y * SEQ + m0) * 80;
#pragma unroll
  for (int i = 0; i < 4; ++i)
#pragma unroll
    for (int j = 0; j < 5; ++j)
      part[pb + (ty * 4 + i) * 80 + tx + 16 * j] = acc[i][j];
}

__global__ __launch_bounds__(256) void gemm2_reduce(
    const float* __restrict__ part, float* __restrict__ xdbl) {
  const int idx = blockIdx.x * 256 + threadIdx.x;  // < SEQ*80
  float s = 0.f;
#pragma unroll
  for (int ks = 0; ks < KS; ++ks) s += part[ks * SEQ * 80 + idx];
  xdbl[idx] = s;
}

// ---------------------------------------------------------------------------
// fp32 GEMM (GEMM3 only): C = softplus(A @ B^T + bias). 64x64 tile, BK=16.
// ---------------------------------------------------------------------------
template <int MODE>
__global__ __launch_bounds__(256) void gemm_kernel(
    const float* __restrict__ A, int lda,
    const float* __restrict__ B, int ldb,
    const float* __restrict__ bias,
    float* __restrict__ C, int ldc,
    int M, int N, int K) {
  __shared__ __align__(16) float As[16][68];
  __shared__ __align__(16) float Bs[16][68];

  const int tid = threadIdx.x;
  const int tx = tid & 15;
  const int ty = tid >> 4;
  const int m0 = blockIdx.y * 64;
  const int n0 = blockIdx.x * 64;

  const int am = tid >> 2;
  const int ak = (tid & 3) << 2;

  float acc[4][4] = {};

  for (int k0 = 0; k0 < K; k0 += 16) {
    {
      const float4 av = *(const float4*)&A[(m0 + am) * lda + k0 + ak];
      As[ak + 0][am] = av.x;
      As[ak + 1][am] = av.y;
      As[ak + 2][am] = av.z;
      As[ak + 3][am] = av.w;
    }
    {
      const int bn = n0 + am;
      float4 bv = make_float4(0.f, 0.f, 0.f, 0.f);
      if (bn < N) bv = *(const float4*)&B[bn * ldb + k0 + ak];
      Bs[ak + 0][am] = bv.x;
      Bs[ak + 1][am] = bv.y;
      Bs[ak + 2][am] = bv.z;
      Bs[ak + 3][am] = bv.w;
    }
    __syncthreads();

#pragma unroll
    for (int k = 0; k < 16; ++k) {
      const float4 a = *(const float4*)&As[k][ty * 4];
      const float4 b = *(const float4*)&Bs[k][tx * 4];
      const float ar[4] = {a.x, a.y, a.z, a.w};
      const float br[4] = {b.x, b.y, b.z, b.w};
#pragma unroll
      for (int i = 0; i < 4; ++i)
#pragma unroll
        for (int j = 0; j < 4; ++j) acc[i][j] = fmaf(ar[i], br[j], acc[i][j]);
    }
    __syncthreads();
  }

#pragma unroll
  for (int i = 0; i < 4; ++i) {
    const int m = m0 + ty * 4 + i;
#pragma unroll
    for (int j = 0; j < 4; ++j) {
      const int n = n0 + tx * 4 + j;
      if (n < N) {
        float v = acc[i][j];
        if (MODE == 1) {
          v += bias[n];
          v = (v > 20.f) ? v : log1pf(__expf(v));  // softplus
        }
        C[m * ldc + n] = v;
      }
    }
  }
}

// ---------------------------------------------------------------------------
// Depthwise causal conv (width 4) + bias + SiLU, vectorized x4 channels.
// ---------------------------------------------------------------------------
__global__ __launch_bounds__(256) void conv_silu_kernel(
    const float* __restrict__ xz, const float* __restrict__ cw,
    const float* __restrict__ cb, float* __restrict__ xbc) {
  const int idx = blockIdx.x * 256 + threadIdx.x;  // < SEQ * D_INNER/4
  const int t = idx / (D_INNER / 4);
  const int d = (idx - t * (D_INNER / 4)) * 4;
  const float4 w0 = *(const float4*)&cw[(d + 0) * 4];
  const float4 w1 = *(const float4*)&cw[(d + 1) * 4];
  const float4 w2 = *(const float4*)&cw[(d + 2) * 4];
  const float4 w3 = *(const float4*)&cw[(d + 3) * 4];
  float4 acc = *(const float4*)&cb[d];
#pragma unroll
  for (int j = 0; j < 4; ++j) {
    const int tt = t + j - 3;
    if (tt >= 0) {
      const float4 xv = *(const float4*)&xz[tt * (2 * D_INNER) + d];
      acc.x = fmaf(xv.x, ((const float*)&w0)[j], acc.x);
      acc.y = fmaf(xv.y, ((const float*)&w1)[j], acc.y);
      acc.z = fmaf(xv.z, ((const float*)&w2)[j], acc.z);
      acc.w = fmaf(xv.w, ((const float*)&w3)[j], acc.w);
    }
  }
  float4 r;
  r.x = acc.x / (1.f + __expf(-acc.x));
  r.y = acc.y / (1.f + __expf(-acc.y));
  r.z = acc.z / (1.f + __expf(-acc.z));
  r.w = acc.w / (1.f + __expf(-acc.w));
  *(float4*)&xbc[t * D_INNER + d] = r;
}

// ---------------------------------------------------------------------------
// Chunked selective scan, phase 1: per (chunk, d-group) local scan from h=0.
// Transposed LDS [ch][t] -> b128 reads over 4 timesteps.
// ---------------------------------------------------------------------------
__global__ __launch_bounds__(256) void scan_part1(
    const float* __restrict__ dt, const float* __restrict__ xdbl,
    const float* __restrict__ xbc, const float* __restrict__ A_log,
    float* __restrict__ aprod, float* __restrict__ hloc) {
  __shared__ __align__(16) float dt_s[16][68];
  __shared__ __align__(16) float xb_s[16][68];
  __shared__ __align__(16) float B_s[16][68];

  const int tid = threadIdx.x;
  const int ch = tid >> 4;
  const int n = tid & 15;
  const int d0 = blockIdx.x * 16;
  const int c = blockIdx.y;
  const int t0 = c * LC;

  // hoist the per-lane constant load so its latency hides under staging
  const float alog = A_log[(d0 + ch) * D_STATE + n];

  for (int f = tid; f < LC * 16; f += 256) {
    const int t = f >> 4, cc = f & 15;
    const int gt = t0 + t;
    dt_s[cc][t] = dt[gt * D_INNER + d0 + cc];
    xb_s[cc][t] = xbc[gt * D_INNER + d0 + cc];
    B_s[cc][t] = xdbl[gt * 80 + DT_RANK + cc];
  }
  __syncthreads();

  const float Aval = -__expf(alog);
  float h = 0.f, ap = 1.f;
  for (int t4 = 0; t4 < LC; t4 += 4) {
    const float4 dtv = *(const float4*)&dt_s[ch][t4];
    const float4 xbv = *(const float4*)&xb_s[ch][t4];
    const float4 Bv = *(const float4*)&B_s[n][t4];
#pragma unroll
    for (int j = 0; j < 4; ++j) {
      const float sdt = ((const float*)&dtv)[j];
      const float dA = __expf(sdt * Aval);
      h = fmaf(dA, h, sdt * ((const float*)&Bv)[j] * ((const float*)&xbv)[j]);
      ap *= dA;
    }
  }
  const int idx = c * DN + d0 * 16 + tid;
  aprod[idx] = ap;
  hloc[idx] = h;
}

// ---------------------------------------------------------------------------
// Phase 2: sequential combine over the NC chunk summaries per (d,n).
// ---------------------------------------------------------------------------
__global__ __launch_bounds__(256) void scan_combine(
    const float* __restrict__ aprod, const float* __restrict__ hloc,
    float* __restrict__ hstart) {
  const int idx = blockIdx.x * 256 + threadIdx.x;  // < DN
  float hs = 0.f;
#pragma unroll
  for (int c = 0; c < NC; ++c) {
    const float a = aprod[c * DN + idx];
    const float hl = hloc[c * DN + idx];
    hstart[c * DN + idx] = hs;
    hs = fmaf(a, hs, hl);
  }
}

// ---------------------------------------------------------------------------
// Phase 3: re-scan each chunk from its true h_start. Transposed LDS [ch][t],
// DPP butterfly reduce, prefetched h/A_log/z (latency hidden under staging /
// t-loop), silu(z)/D epilogue in the vectorized writeout. Writes ym as bf16
// hi/lo for GEMM4.
// ---------------------------------------------------------------------------
__global__ __launch_bounds__(256) void scan_part3(
    const float* __restrict__ dt, const float* __restrict__ xdbl,
    const float* __restrict__ xbc, const float* __restrict__ xz,
    const float* __restrict__ A_log, const float* __restrict__ Dp,
    const float* __restrict__ hstart,
    ushort* __restrict__ ym_hi, ushort* __restrict__ ym_lo) {
  __shared__ __align__(16) float dt_s[16][68];
  __shared__ __align__(16) float xb_s[16][68];
  __shared__ __align__(16) float B_s[16][68];
  __shared__ __align__(16) float C_s[16][68];
  __shared__ float y_s[LC][16];

  const int tid = threadIdx.x;
  const int ch = tid >> 4;
  const int n = tid & 15;
  const int d0 = blockIdx.x * 16;
  const int c = blockIdx.y;
  const int t0 = c * LC;

  // early loads: h_start, A_log, z (used only in writeout), D
  float h = hstart[c * DN + d0 * 16 + tid];
  const float alog = A_log[(d0 + ch) * D_STATE + n];
  float zpf[4], dpf[4];
#pragma unroll
  for (int u = 0; u < 4; ++u) {
    const int f = u * 256 + tid;
    const int t = f >> 4, cc = f & 15;
    zpf[u] = xz[(size_t)(t0 + t) * (2 * D_INNER) + D_INNER + d0 + cc];
    dpf[u] = Dp[d0 + cc];
  }

  for (int f = tid; f < LC * 16; f += 256) {
    const int t = f >> 4, cc = f & 15;
    const int gt = t0 + t;
    dt_s[cc][t] = dt[gt * D_INNER + d0 + cc];
    xb_s[cc][t] = xbc[gt * D_INNER + d0 + cc];
    B_s[cc][t] = xdbl[gt * 80 + DT_RANK + cc];
    C_s[cc][t] = xdbl[gt * 80 + DT_RANK + D_STATE + cc];
  }
  __syncthreads();

  const float Aval = -__expf(alog);

  for (int t4 = 0; t4 < LC; t4 += 4) {
    const float4 dtv = *(const float4*)&dt_s[ch][t4];
    const float4 xbv = *(const float4*)&xb_s[ch][t4];
    const float4 Bv = *(const float4*)&B_s[n][t4];
    const float4 Cv = *(const float4*)&C_s[n][t4];
#pragma unroll
    for (int j = 0; j < 4; ++j) {
      const float sdt = ((const float*)&dtv)[j];
      const float dA = __expf(sdt * Aval);
      h = fmaf(dA, h, sdt * ((const float*)&Bv)[j] * ((const float*)&xbv)[j]);
      const float p = dpp_radd16(h * ((const float*)&Cv)[j]);
      if (n == 0) y_s[t4 + j][ch] = p;
    }
  }
  __syncthreads();

  // writeout: apply +xb*D and *silu(z), split to bf16 hi/lo
#pragma unroll
  for (int u = 0; u < 4; ++u) {
    const int f = u * 256 + tid;
    const int t = f >> 4, cc = f & 15;
    const int gt = t0 + t;
    const float zz = zpf[u];
    const float sig = 1.f / (1.f + __expf(-zz));
    const float v = (y_s[t][cc] + xb_s[cc][t] * dpf[u]) * (zz * sig);
    const ushort hb = f2bf_bits(v);
    const int gidx = gt * D_INNER + d0 + cc;
    ym_hi[gidx] = hb;
    ym_lo[gidx] = f2bf_bits(v - bf_bits2f(hb));
  }
}

// ---------------------------------------------------------------------------
extern "C" void kernel_launch(void* const* d_in, const int* in_sizes, int n_in,
                              void* d_out, int out_size, void* d_ws,
                              size_t ws_size, hipStream_t stream) {
  const float* x = (const float*)d_in[0];       // (2048, 768)
  const float* W_in = (const float*)d_in[1];    // (3072, 768)
  const float* conv_w = (const float*)d_in[2];  // (1536, 1, 4)
  const float* conv_b = (const float*)d_in[3];  // (1536,)
  const float* W_x = (const float*)d_in[4];     // (80, 1536)
  const float* W_dt = (const float*)d_in[5];    // (1536, 48)
  const float* b_dt = (const float*)d_in[6];    // (1536,)
  const float* A_log = (const float*)d_in[7];   // (1536, 16)
  const float* D_param = (const float*)d_in[8]; // (1536,)
  const float* W_out = (const float*)d_in[9];   // (768, 1536)
  float* out = (float*)d_out;                   // (2048, 768)

  // ---- workspace layout (fp32 region, then bf16 hi/lo region) ----
  float* ws = (float*)d_ws;
  float* xz = ws;                            // 2048*3072
  float* xbc = xz + SEQ * 2 * D_INNER;       // 2048*1536
  float* xdbl = xbc + SEQ * D_INNER;         // 2048*80
  float* dtb = xdbl + SEQ * 80;              // 2048*1536
  float* aprod = dtb + SEQ * D_INNER;        // NC*DN
  float* hloc = aprod + NC * DN;             // NC*DN
  float* hstart = hloc + NC * DN;            // NC*DN

  ushort* x_hi = (ushort*)(hstart + NC * DN);       // 2048*768
  ushort* x_lo = x_hi + SEQ * D_MODEL;
  ushort* wi_hi = x_lo + SEQ * D_MODEL;             // 3072*768
  ushort* wi_lo = wi_hi + 2 * D_INNER * D_MODEL;
  ushort* wo_hi = wi_lo + 2 * D_INNER * D_MODEL;    // 768*1536
  ushort* wo_lo = wo_hi + D_MODEL * D_INNER;
  ushort* ym_hi = wo_lo + D_MODEL * D_INNER;        // 2048*1536
  ushort* ym_lo = ym_hi + SEQ * D_INNER;

  // GEMM2 split-K partials alias the x_hi/x_lo region (dead after GEMM1).
  float* part = (float*)x_hi;

  const dim3 blk(256);

  // ---- pre-split x, W_in, W_out into bf16 hi/lo (single fused launch) ----
  const int n0v = SEQ * D_MODEL / 4;            // 393216
  const int n1v = 2 * D_INNER * D_MODEL / 4;    // 589824
  const int n2v = D_MODEL * D_INNER / 4;        // 294912
  split3_bf16_kernel<<<dim3((n0v + n1v + n2v) / 256), blk, 0, stream>>>(
      x, x_hi, x_lo, n0v, W_in, wi_hi, wi_lo, n1v, W_out, wo_hi, wo_lo);

  // xz = x @ W_in^T   (2048 x 3072), MFMA pre-split + gload_lds, 128x64 tile
  // -> 768 blocks = 3.0/CU exact
  gemm_mfma_presplit<128, 64><<<dim3(2 * D_INNER / 64, SEQ / 128), blk, 0, stream>>>(
      x_hi, x_lo, D_MODEL, wi_hi, wi_lo, D_MODEL, xz, 2 * D_INNER, D_MODEL);

  // xbc = silu(causal_conv(xb) + conv_b), x4 vectorized
  conv_silu_kernel<<<dim3(SEQ * D_INNER / 1024), blk, 0, stream>>>(
      xz, conv_w, conv_b, xbc);

  // xdbl = xbc @ W_x^T   (2048 x 80), 8-way split-K + reduce
  gemm2_splitk<<<dim3(SEQ / 64, KS), blk, 0, stream>>>(xbc, W_x, part);
  gemm2_reduce<<<dim3(SEQ * 80 / 256), blk, 0, stream>>>(part, xdbl);

  // dtb = softplus(xdbl[:, :48] @ W_dt^T + b_dt)   (2048 x 1536), fp32
  gemm_kernel<1><<<dim3(D_INNER / 64, SEQ / 64), blk, 0, stream>>>(
      xdbl, 80, W_dt, DT_RANK, b_dt, dtb, D_INNER, SEQ, D_INNER, DT_RANK);

  // chunked scan: local scans -> combine -> finalize (writes ym as hi/lo)
  scan_part1<<<dim3(D_INNER / 16, NC), blk, 0, stream>>>(
      dtb, xdbl, xbc, A_log, aprod, hloc);
  scan_combine<<<dim3(DN / 256), blk, 0, stream>>>(aprod, hloc, hstart);
  scan_part3<<<dim3(D_INNER / 16, NC), blk, 0, stream>>>(
      dtb, xdbl, xbc, xz, A_log, D_param, hstart, ym_hi, ym_lo);

  // out = ym @ W_out^T   (2048 x 768), MFMA pre-split + gload_lds
  gemm_mfma_presplit<64, 64><<<dim3(D_MODEL / 64, SEQ / 64), blk, 0, stream>>>(
      ym_hi, ym_lo, D_INNER, wo_hi, wo_lo, D_INNER, out, D_MODEL, D_INNER);
}

// Round 12
// 259.691 us; speedup vs baseline: 3.5865x; 1.0225x over previous
//
#include <hip/hip_runtime.h>
#include <hip/hip_bf16.h>

#define D_MODEL 768
#define D_INNER 1536
#define D_STATE 16
#define DT_RANK 48
#define SEQ 2048
#define NC 32            // scan chunks
#define LC (SEQ / NC)    // 64 timesteps per chunk
#define DN (D_INNER * D_STATE)  // 24576 (d,n) pairs
#define KS 8             // GEMM2 split-K ways
#define KCH (D_INNER / KS)  // 192

typedef float f32x4 __attribute__((ext_vector_type(4)));
typedef short bf16x8 __attribute__((ext_vector_type(8)));

typedef const __attribute__((address_space(1))) unsigned int* gas_u32;
typedef __attribute__((address_space(3))) unsigned int* las_u32;

// async global->LDS, 16B per lane; LDS dest = uniform base + lane*16 (m104)
__device__ __forceinline__ void gload16(const void* g, void* l) {
  __builtin_amdgcn_global_load_lds((gas_u32)g, (las_u32)l, 16, 0, 0);
}

// Butterfly all-reduce (sum) over each 16-lane group, pure DPP (no LDS ops).
__device__ __forceinline__ float dpp_radd16(float v) {
  int x;
  x = __builtin_amdgcn_update_dpp(0, __float_as_int(v), 0xB1, 0xF, 0xF, true);  // quad_perm xor1
  v += __int_as_float(x);
  x = __builtin_amdgcn_update_dpp(0, __float_as_int(v), 0x4E, 0xF, 0xF, true);  // quad_perm xor2
  v += __int_as_float(x);
  x = __builtin_amdgcn_update_dpp(0, __float_as_int(v), 0x141, 0xF, 0xF, true); // row_half_mirror
  v += __int_as_float(x);
  x = __builtin_amdgcn_update_dpp(0, __float_as_int(v), 0x140, 0xF, 0xF, true); // row_mirror
  v += __int_as_float(x);
  return v;
}

// round-to-nearest-even fp32 -> bf16 bits
__device__ __forceinline__ ushort f2bf_bits(float f) {
  uint u = __float_as_uint(f);
  u += 0x7FFFu + ((u >> 16) & 1u);
  return (ushort)(u >> 16);
}
__device__ __forceinline__ float bf_bits2f(ushort b) {
  return __uint_as_float(((uint)b) << 16);
}

__device__ __forceinline__ void split_vec4(const float* __restrict__ src,
                                           ushort* __restrict__ hi,
                                           ushort* __restrict__ lo, int idx) {
  const float4 v = ((const float4*)src)[idx];
  const float f[4] = {v.x, v.y, v.z, v.w};
  ushort4 h, l;
  ushort* hp = (ushort*)&h;
  ushort* lp = (ushort*)&l;
#pragma unroll
  for (int j = 0; j < 4; ++j) {
    const ushort hb = f2bf_bits(f[j]);
    hp[j] = hb;
    lp[j] = f2bf_bits(f[j] - bf_bits2f(hb));
  }
  ((ushort4*)hi)[idx] = h;
  ((ushort4*)lo)[idx] = l;
}

// ---------------------------------------------------------------------------
// Fused fp32 -> (hi,lo) bf16 split of three tensors (x, W_in, W_out).
// ---------------------------------------------------------------------------
__global__ __launch_bounds__(256) void split3_bf16_kernel(
    const float* __restrict__ s0, ushort* __restrict__ h0, ushort* __restrict__ l0, int n0v,
    const float* __restrict__ s1, ushort* __restrict__ h1, ushort* __restrict__ l1, int n1v,
    const float* __restrict__ s2, ushort* __restrict__ h2, ushort* __restrict__ l2) {
  int idx = blockIdx.x * 256 + threadIdx.x;
  if (idx < n0v) {
    split_vec4(s0, h0, l0, idx);
  } else if (idx < n0v + n1v) {
    split_vec4(s1, h1, l1, idx - n0v);
  } else {
    split_vec4(s2, h2, l2, idx - n0v - n1v);
  }
}

// ---------------------------------------------------------------------------
// MFMA GEMM on pre-split bf16 hi/lo operands, global_load_lds staging with
// XOR-swizzle (rule #21 both-sides pairing): LDS dest LINEAR (gload_lds
// requirement), global SOURCE column pre-swizzled by slot^=(row&7), fragment
// read applies the same involution. Kills the 16-way same-column bank
// conflict of 128B rows (G4 / m136) while keeping coalescing.
// C = Ahi·Bhi^T + Ahi·Blo^T + Alo·Bhi^T   (3-term Ootomo split)
// ---------------------------------------------------------------------------
template <int BM, int BN>
__global__ __launch_bounds__(256) void gemm_mfma_presplit(
    const ushort* __restrict__ Ah, const ushort* __restrict__ Al, int lda,
    const ushort* __restrict__ Bh, const ushort* __restrict__ Bl, int ldb,
    float* __restrict__ C, int ldc, int K) {
  __shared__ __align__(16) ushort As_hi[BM * 64];
  __shared__ __align__(16) ushort As_lo[BM * 64];
  __shared__ __align__(16) ushort Bs_hi[BN * 64];
  __shared__ __align__(16) ushort Bs_lo[BN * 64];

  const int tid = threadIdx.x;
  const int lane = tid & 63;
  const int wave = tid >> 6;
  const int wbase = tid & 192;  // wave*64, uniform within wave
  const int m0 = blockIdx.y * BM;
  const int n0 = blockIdx.x * BN;

  constexpr int FM = BM / 32;
  constexpr int FN = BN / 32;
  const int wm0 = (wave >> 1) * (BM / 2);
  const int wn0 = (wave & 1) * (BN / 2);
  const int fr = lane & 15;
  const int kg = lane >> 4;

  f32x4 acc[FM][FN] = {};

  for (int k0 = 0; k0 < K; k0 += 64) {
    // ---- stage: linear LDS dest, source column swizzled slot^=(row&7) ----
#pragma unroll
    for (int i = 0; i < BM / 32; ++i) {
      const int slot = i * 256 + tid;
      const int row = slot >> 3;
      const int c8 = ((slot & 7) ^ (row & 7)) << 3;  // pre-swizzled source col
      const size_t g = (size_t)(m0 + row) * lda + k0 + c8;
      const int lb = (i * 256 + wbase) * 8;  // wave-uniform LDS base slot
      gload16(&Ah[g], &As_hi[lb]);
      gload16(&Al[g], &As_lo[lb]);
    }
#pragma unroll
    for (int i = 0; i < BN / 32; ++i) {
      const int slot = i * 256 + tid;
      const int row = slot >> 3;
      const int c8 = ((slot & 7) ^ (row & 7)) << 3;
      const size_t g = (size_t)(n0 + row) * ldb + k0 + c8;
      const int lb = (i * 256 + wbase) * 8;
      gload16(&Bh[g], &Bs_hi[lb]);
      gload16(&Bl[g], &Bs_lo[lb]);
    }
    __syncthreads();

#pragma unroll
    for (int k2 = 0; k2 < 64; k2 += 32) {
      const int gslot = (k2 >> 3) + kg;  // logical 16B slot within the row
      bf16x8 ah[FM], al[FM];
#pragma unroll
      for (int m = 0; m < FM; ++m) {
        const int row = wm0 + m * 16 + fr;
        const int base = row * 64 + ((gslot ^ (row & 7)) << 3);
        ah[m] = *(const bf16x8*)&As_hi[base];
        al[m] = *(const bf16x8*)&As_lo[base];
      }
#pragma unroll
      for (int n = 0; n < FN; ++n) {
        const int row = wn0 + n * 16 + fr;
        const int base = row * 64 + ((gslot ^ (row & 7)) << 3);
        const bf16x8 bh = *(const bf16x8*)&Bs_hi[base];
        const bf16x8 bl = *(const bf16x8*)&Bs_lo[base];
#pragma unroll
        for (int m = 0; m < FM; ++m) {
          acc[m][n] = __builtin_amdgcn_mfma_f32_16x16x32_bf16(ah[m], bh, acc[m][n], 0, 0, 0);
          acc[m][n] = __builtin_amdgcn_mfma_f32_16x16x32_bf16(ah[m], bl, acc[m][n], 0, 0, 0);
          acc[m][n] = __builtin_amdgcn_mfma_f32_16x16x32_bf16(al[m], bh, acc[m][n], 0, 0, 0);
        }
      }
    }
    __syncthreads();
  }

  // C/D layout: col = lane&15, row = (lane>>4)*4 + reg   [m89]
#pragma unroll
  for (int m = 0; m < FM; ++m) {
#pragma unroll
    for (int n = 0; n < FN; ++n) {
      const int row = m0 + wm0 + m * 16 + (lane >> 4) * 4;
      const int col = n0 + wn0 + n * 16 + (lane & 15);
#pragma unroll
      for (int r = 0; r < 4; ++r) C[(row + r) * ldc + col] = acc[m][n][r];
    }
  }
}

// ---------------------------------------------------------------------------
// GEMM2 split-K: part[ks] = xbc[:, ks*192:(ks+1)*192] @ W_x[:, same]^T
// ---------------------------------------------------------------------------
__global__ __launch_bounds__(256) void gemm2_splitk(
    const float* __restrict__ A,   // xbc (SEQ, D_INNER)
    const float* __restrict__ B,   // W_x (80, D_INNER)
    float* __restrict__ part) {    // (KS, SEQ, 80)
  __shared__ __align__(16) float As[16][68];
  __shared__ __align__(16) float Bs[16][84];

  const int tid = threadIdx.x;
  const int tx = tid & 15;
  const int ty = tid >> 4;
  const int m0 = blockIdx.x * 64;
  const int kbase = blockIdx.y * KCH;

  float acc[4][5] = {};

  for (int k0 = 0; k0 < KCH; k0 += 16) {
    {  // stage A 64x16
      const int am = tid >> 2;
      const int ak = (tid & 3) << 2;
      const float4 av = *(const float4*)&A[(m0 + am) * D_INNER + kbase + k0 + ak];
      As[ak + 0][am] = av.x;
      As[ak + 1][am] = av.y;
      As[ak + 2][am] = av.z;
      As[ak + 3][am] = av.w;
    }
    // stage B 80x16
    for (int f = tid; f < 80 * 4; f += 256) {
      const int row = f >> 2;
      const int kk = (f & 3) << 2;
      const float4 bv = *(const float4*)&B[row * D_INNER + kbase + k0 + kk];
      Bs[kk + 0][row] = bv.x;
      Bs[kk + 1][row] = bv.y;
      Bs[kk + 2][row] = bv.z;
      Bs[kk + 3][row] = bv.w;
    }
    __syncthreads();

#pragma unroll
    for (int k = 0; k < 16; ++k) {
      const float4 a4 = *(const float4*)&As[k][ty * 4];
      const float a[4] = {a4.x, a4.y, a4.z, a4.w};
      float b[5];
#pragma unroll
      for (int j = 0; j < 5; ++j) b[j] = Bs[k][tx + 16 * j];
#pragma unroll
      for (int i = 0; i < 4; ++i)
#pragma unroll
        for (int j = 0; j < 5; ++j) acc[i][j] = fmaf(a[i], b[j], acc[i][j]);
    }
    __syncthreads();
  }

  const int pb = (blockIdx.y * SEQ + m0) * 80;
#pragma unroll
  for (int i = 0; i < 4; ++i)
#pragma unroll
    for (int j = 0; j < 5; ++j)
      part[pb + (ty * 4 + i) * 80 + tx + 16 * j] = acc[i][j];
}

__global__ __launch_bounds__(256) void gemm2_reduce(
    const float* __restrict__ part, float* __restrict__ xdbl) {
  const int idx = blockIdx.x * 256 + threadIdx.x;  // < SEQ*80
  float s = 0.f;
#pragma unroll
  for (int ks = 0; ks < KS; ++ks) s += part[ks * SEQ * 80 + idx];
  xdbl[idx] = s;
}

// ---------------------------------------------------------------------------
// fp32 GEMM (GEMM3 only): C = softplus(A @ B^T + bias). 64x64 tile, BK=16.
// ---------------------------------------------------------------------------
template <int MODE>
__global__ __launch_bounds__(256) void gemm_kernel(
    const float* __restrict__ A, int lda,
    const float* __restrict__ B, int ldb,
    const float* __restrict__ bias,
    float* __restrict__ C, int ldc,
    int M, int N, int K) {
  __shared__ __align__(16) float As[16][68];
  __shared__ __align__(16) float Bs[16][68];

  const int tid = threadIdx.x;
  const int tx = tid & 15;
  const int ty = tid >> 4;
  const int m0 = blockIdx.y * 64;
  const int n0 = blockIdx.x * 64;

  const int am = tid >> 2;
  const int ak = (tid & 3) << 2;

  float acc[4][4] = {};

  for (int k0 = 0; k0 < K; k0 += 16) {
    {
      const float4 av = *(const float4*)&A[(m0 + am) * lda + k0 + ak];
      As[ak + 0][am] = av.x;
      As[ak + 1][am] = av.y;
      As[ak + 2][am] = av.z;
      As[ak + 3][am] = av.w;
    }
    {
      const int bn = n0 + am;
      float4 bv = make_float4(0.f, 0.f, 0.f, 0.f);
      if (bn < N) bv = *(const float4*)&B[bn * ldb + k0 + ak];
      Bs[ak + 0][am] = bv.x;
      Bs[ak + 1][am] = bv.y;
      Bs[ak + 2][am] = bv.z;
      Bs[ak + 3][am] = bv.w;
    }
    __syncthreads();

#pragma unroll
    for (int k = 0; k < 16; ++k) {
      const float4 a = *(const float4*)&As[k][ty * 4];
      const float4 b = *(const float4*)&Bs[k][tx * 4];
      const float ar[4] = {a.x, a.y, a.z, a.w};
      const float br[4] = {b.x, b.y, b.z, b.w};
#pragma unroll
      for (int i = 0; i < 4; ++i)
#pragma unroll
        for (int j = 0; j < 4; ++j) acc[i][j] = fmaf(ar[i], br[j], acc[i][j]);
    }
    __syncthreads();
  }

#pragma unroll
  for (int i = 0; i < 4; ++i) {
    const int m = m0 + ty * 4 + i;
#pragma unroll
    for (int j = 0; j < 4; ++j) {
      const int n = n0 + tx * 4 + j;
      if (n < N) {
        float v = acc[i][j];
        if (MODE == 1) {
          v += bias[n];
          v = (v > 20.f) ? v : log1pf(__expf(v));  // softplus
        }
        C[m * ldc + n] = v;
      }
    }
  }
}

// ---------------------------------------------------------------------------
// Depthwise causal conv (width 4) + bias + SiLU, vectorized x4 channels.
// ---------------------------------------------------------------------------
__global__ __launch_bounds__(256) void conv_silu_kernel(
    const float* __restrict__ xz, const float* __restrict__ cw,
    const float* __restrict__ cb, float* __restrict__ xbc) {
  const int idx = blockIdx.x * 256 + threadIdx.x;  // < SEQ * D_INNER/4
  const int t = idx / (D_INNER / 4);
  const int d = (idx - t * (D_INNER / 4)) * 4;
  const float4 w0 = *(const float4*)&cw[(d + 0) * 4];
  const float4 w1 = *(const float4*)&cw[(d + 1) * 4];
  const float4 w2 = *(const float4*)&cw[(d + 2) * 4];
  const float4 w3 = *(const float4*)&cw[(d + 3) * 4];
  float4 acc = *(const float4*)&cb[d];
#pragma unroll
  for (int j = 0; j < 4; ++j) {
    const int tt = t + j - 3;
    if (tt >= 0) {
      const float4 xv = *(const float4*)&xz[tt * (2 * D_INNER) + d];
      acc.x = fmaf(xv.x, ((const float*)&w0)[j], acc.x);
      acc.y = fmaf(xv.y, ((const float*)&w1)[j], acc.y);
      acc.z = fmaf(xv.z, ((const float*)&w2)[j], acc.z);
      acc.w = fmaf(xv.w, ((const float*)&w3)[j], acc.w);
    }
  }
  float4 r;
  r.x = acc.x / (1.f + __expf(-acc.x));
  r.y = acc.y / (1.f + __expf(-acc.y));
  r.z = acc.z / (1.f + __expf(-acc.z));
  r.w = acc.w / (1.f + __expf(-acc.w));
  *(float4*)&xbc[t * D_INNER + d] = r;
}

// ---------------------------------------------------------------------------
// Chunked selective scan, phase 1: per (chunk, d-group) local scan from h=0.
// Transposed LDS [ch][t] -> b128 reads over 4 timesteps.
// ---------------------------------------------------------------------------
__global__ __launch_bounds__(256) void scan_part1(
    const float* __restrict__ dt, const float* __restrict__ xdbl,
    const float* __restrict__ xbc, const float* __restrict__ A_log,
    float* __restrict__ aprod, float* __restrict__ hloc) {
  __shared__ __align__(16) float dt_s[16][68];
  __shared__ __align__(16) float xb_s[16][68];
  __shared__ __align__(16) float B_s[16][68];

  const int tid = threadIdx.x;
  const int ch = tid >> 4;
  const int n = tid & 15;
  const int d0 = blockIdx.x * 16;
  const int c = blockIdx.y;
  const int t0 = c * LC;

  const float alog = A_log[(d0 + ch) * D_STATE + n];

  for (int f = tid; f < LC * 16; f += 256) {
    const int t = f >> 4, cc = f & 15;
    const int gt = t0 + t;
    dt_s[cc][t] = dt[gt * D_INNER + d0 + cc];
    xb_s[cc][t] = xbc[gt * D_INNER + d0 + cc];
    B_s[cc][t] = xdbl[gt * 80 + DT_RANK + cc];
  }
  __syncthreads();

  const float Aval = -__expf(alog);
  float h = 0.f, ap = 1.f;
  for (int t4 = 0; t4 < LC; t4 += 4) {
    const float4 dtv = *(const float4*)&dt_s[ch][t4];
    const float4 xbv = *(const float4*)&xb_s[ch][t4];
    const float4 Bv = *(const float4*)&B_s[n][t4];
#pragma unroll
    for (int j = 0; j < 4; ++j) {
      const float sdt = ((const float*)&dtv)[j];
      const float dA = __expf(sdt * Aval);
      h = fmaf(dA, h, sdt * ((const float*)&Bv)[j] * ((const float*)&xbv)[j]);
      ap *= dA;
    }
  }
  const int idx = c * DN + d0 * 16 + tid;
  aprod[idx] = ap;
  hloc[idx] = h;
}

// ---------------------------------------------------------------------------
// Phase 2: sequential combine over the NC chunk summaries per (d,n).
// ---------------------------------------------------------------------------
__global__ __launch_bounds__(256) void scan_combine(
    const float* __restrict__ aprod, const float* __restrict__ hloc,
    float* __restrict__ hstart) {
  const int idx = blockIdx.x * 256 + threadIdx.x;  // < DN
  float hs = 0.f;
#pragma unroll
  for (int c = 0; c < NC; ++c) {
    const float a = aprod[c * DN + idx];
    const float hl = hloc[c * DN + idx];
    hstart[c * DN + idx] = hs;
    hs = fmaf(a, hs, hl);
  }
}

// ---------------------------------------------------------------------------
// Phase 3: re-scan each chunk from its true h_start. Transposed LDS [ch][t],
// DPP butterfly reduce, prefetched h/A_log/z, silu(z)/D epilogue in the
// vectorized writeout. Writes ym as bf16 hi/lo for GEMM4.
// ---------------------------------------------------------------------------
__global__ __launch_bounds__(256) void scan_part3(
    const float* __restrict__ dt, const float* __restrict__ xdbl,
    const float* __restrict__ xbc, const float* __restrict__ xz,
    const float* __restrict__ A_log, const float* __restrict__ Dp,
    const float* __restrict__ hstart,
    ushort* __restrict__ ym_hi, ushort* __restrict__ ym_lo) {
  __shared__ __align__(16) float dt_s[16][68];
  __shared__ __align__(16) float xb_s[16][68];
  __shared__ __align__(16) float B_s[16][68];
  __shared__ __align__(16) float C_s[16][68];
  __shared__ float y_s[LC][16];

  const int tid = threadIdx.x;
  const int ch = tid >> 4;
  const int n = tid & 15;
  const int d0 = blockIdx.x * 16;
  const int c = blockIdx.y;
  const int t0 = c * LC;

  float h = hstart[c * DN + d0 * 16 + tid];
  const float alog = A_log[(d0 + ch) * D_STATE + n];
  float zpf[4], dpf[4];
#pragma unroll
  for (int u = 0; u < 4; ++u) {
    const int f = u * 256 + tid;
    const int t = f >> 4, cc = f & 15;
    zpf[u] = xz[(size_t)(t0 + t) * (2 * D_INNER) + D_INNER + d0 + cc];
    dpf[u] = Dp[d0 + cc];
  }

  for (int f = tid; f < LC * 16; f += 256) {
    const int t = f >> 4, cc = f & 15;
    const int gt = t0 + t;
    dt_s[cc][t] = dt[gt * D_INNER + d0 + cc];
    xb_s[cc][t] = xbc[gt * D_INNER + d0 + cc];
    B_s[cc][t] = xdbl[gt * 80 + DT_RANK + cc];
    C_s[cc][t] = xdbl[gt * 80 + DT_RANK + D_STATE + cc];
  }
  __syncthreads();

  const float Aval = -__expf(alog);

  for (int t4 = 0; t4 < LC; t4 += 4) {
    const float4 dtv = *(const float4*)&dt_s[ch][t4];
    const float4 xbv = *(const float4*)&xb_s[ch][t4];
    const float4 Bv = *(const float4*)&B_s[n][t4];
    const float4 Cv = *(const float4*)&C_s[n][t4];
#pragma unroll
    for (int j = 0; j < 4; ++j) {
      const float sdt = ((const float*)&dtv)[j];
      const float dA = __expf(sdt * Aval);
      h = fmaf(dA, h, sdt * ((const float*)&Bv)[j] * ((const float*)&xbv)[j]);
      const float p = dpp_radd16(h * ((const float*)&Cv)[j]);
      if (n == 0) y_s[t4 + j][ch] = p;
    }
  }
  __syncthreads();

#pragma unroll
  for (int u = 0; u < 4; ++u) {
    const int f = u * 256 + tid;
    const int t = f >> 4, cc = f & 15;
    const int gt = t0 + t;
    const float zz = zpf[u];
    const float sig = 1.f / (1.f + __expf(-zz));
    const float v = (y_s[t][cc] + xb_s[cc][t] * dpf[u]) * (zz * sig);
    const ushort hb = f2bf_bits(v);
    const int gidx = gt * D_INNER + d0 + cc;
    ym_hi[gidx] = hb;
    ym_lo[gidx] = f2bf_bits(v - bf_bits2f(hb));
  }
}

// ---------------------------------------------------------------------------
extern "C" void kernel_launch(void* const* d_in, const int* in_sizes, int n_in,
                              void* d_out, int out_size, void* d_ws,
                              size_t ws_size, hipStream_t stream) {
  const float* x = (const float*)d_in[0];       // (2048, 768)
  const float* W_in = (const float*)d_in[1];    // (3072, 768)
  const float* conv_w = (const float*)d_in[2];  // (1536, 1, 4)
  const float* conv_b = (const float*)d_in[3];  // (1536,)
  const float* W_x = (const float*)d_in[4];     // (80, 1536)
  const float* W_dt = (const float*)d_in[5];    // (1536, 48)
  const float* b_dt = (const float*)d_in[6];    // (1536,)
  const float* A_log = (const float*)d_in[7];   // (1536, 16)
  const float* D_param = (const float*)d_in[8]; // (1536,)
  const float* W_out = (const float*)d_in[9];   // (768, 1536)
  float* out = (float*)d_out;                   // (2048, 768)

  // ---- workspace layout (fp32 region, then bf16 hi/lo region) ----
  float* ws = (float*)d_ws;
  float* xz = ws;                            // 2048*3072
  float* xbc = xz + SEQ * 2 * D_INNER;       // 2048*1536
  float* xdbl = xbc + SEQ * D_INNER;         // 2048*80
  float* dtb = xdbl + SEQ * 80;              // 2048*1536
  float* aprod = dtb + SEQ * D_INNER;        // NC*DN
  float* hloc = aprod + NC * DN;             // NC*DN
  float* hstart = hloc + NC * DN;            // NC*DN

  ushort* x_hi = (ushort*)(hstart + NC * DN);       // 2048*768
  ushort* x_lo = x_hi + SEQ * D_MODEL;
  ushort* wi_hi = x_lo + SEQ * D_MODEL;             // 3072*768
  ushort* wi_lo = wi_hi + 2 * D_INNER * D_MODEL;
  ushort* wo_hi = wi_lo + 2 * D_INNER * D_MODEL;    // 768*1536
  ushort* wo_lo = wo_hi + D_MODEL * D_INNER;
  ushort* ym_hi = wo_lo + D_MODEL * D_INNER;        // 2048*1536
  ushort* ym_lo = ym_hi + SEQ * D_INNER;

  // GEMM2 split-K partials alias the x_hi/x_lo region (dead after GEMM1).
  float* part = (float*)x_hi;

  const dim3 blk(256);

  // ---- pre-split x, W_in, W_out into bf16 hi/lo (single fused launch) ----
  const int n0v = SEQ * D_MODEL / 4;            // 393216
  const int n1v = 2 * D_INNER * D_MODEL / 4;    // 589824
  const int n2v = D_MODEL * D_INNER / 4;        // 294912
  split3_bf16_kernel<<<dim3((n0v + n1v + n2v) / 256), blk, 0, stream>>>(
      x, x_hi, x_lo, n0v, W_in, wi_hi, wi_lo, n1v, W_out, wo_hi, wo_lo);

  // xz = x @ W_in^T   (2048 x 3072), MFMA pre-split + swizzled gload_lds
  gemm_mfma_presplit<128, 64><<<dim3(2 * D_INNER / 64, SEQ / 128), blk, 0, stream>>>(
      x_hi, x_lo, D_MODEL, wi_hi, wi_lo, D_MODEL, xz, 2 * D_INNER, D_MODEL);

  // xbc = silu(causal_conv(xb) + conv_b), x4 vectorized
  conv_silu_kernel<<<dim3(SEQ * D_INNER / 1024), blk, 0, stream>>>(
      xz, conv_w, conv_b, xbc);

  // xdbl = xbc @ W_x^T   (2048 x 80), 8-way split-K + reduce
  gemm2_splitk<<<dim3(SEQ / 64, KS), blk, 0, stream>>>(xbc, W_x, part);
  gemm2_reduce<<<dim3(SEQ * 80 / 256), blk, 0, stream>>>(part, xdbl);

  // dtb = softplus(xdbl[:, :48] @ W_dt^T + b_dt)   (2048 x 1536), fp32
  gemm_kernel<1><<<dim3(D_INNER / 64, SEQ / 64), blk, 0, stream>>>(
      xdbl, 80, W_dt, DT_RANK, b_dt, dtb, D_INNER, SEQ, D_INNER, DT_RANK);

  // chunked scan: local scans -> combine -> finalize (writes ym as hi/lo)
  scan_part1<<<dim3(D_INNER / 16, NC), blk, 0, stream>>>(
      dtb, xdbl, xbc, A_log, aprod, hloc);
  scan_combine<<<dim3(DN / 256), blk, 0, stream>>>(aprod, hloc, hstart);
  scan_part3<<<dim3(D_INNER / 16, NC), blk, 0, stream>>>(
      dtb, xdbl, xbc, xz, A_log, D_param, hstart, ym_hi, ym_lo);

  // out = ym @ W_out^T   (2048 x 768), MFMA pre-split + swizzled gload_lds
  gemm_mfma_presplit<64, 64><<<dim3(D_MODEL / 64, SEQ / 64), blk, 0, stream>>>(
      ym_hi, ym_lo, D_INNER, wo_hi, wo_lo, D_INNER, out, D_MODEL, D_INNER);
}